// Round 6
// baseline (530.495 us; speedup 1.0000x reference)
//
#include <hip/hip_runtime.h>
#include <hip/hip_bf16.h>

// InfoMultiAttn: B=8192, L=64, E=128, H=8, HD=16. fp32 accumulate.
// Algebraic restructure (35 GFLOP -> ~4.5 GFLOP):
//   scores[h,l] = (u_h . x_l + c_h)/4,  u_h = Wk_h^T q_h,  c_h = q_h . bk_h
//   ctx_h       = Wv_h y_h + bv_h,      y_h = sum_l attn[h,l] x_l
// R5: S4 scores via v_mfma_f32_16x16x32_bf16 (layouts verified in-harness):
//     A row=lane&15 k=(lane>>4)*8+j | B col=lane&15 same k | D col=lane&15,
//     row=(lane>>4)*4+r.
// R6/R7 lessons: no launch_bounds>4 (spills); coalesce weight GEMV loads.
// R8/R9: all matmul phases MFMA (weights direct from global; S6 y=P@X with
//     X-column gather; S1 zero-fills rows>=len so 0*garbage can't NaN).
// R9 post-mortem: VALUBusy 22.6%, Mfma 2.5%, HBM 6% -> latency-bound;
//     Occupancy 42% (3 blocks LDS-capped, ~1.7 avg resident). Stall floor
//     ~130us dominates; instruction cuts return ~3%.
// R10: NB=1 batch/block. LDS ~25KB -> 4 blocks/CU = 32 waves = 100%
//     occupancy (thread-capped; VGPR 52<=64 ok). Grid 8192. Weight traffic
//     doubles (L2-cached, not the bottleneck). Phases S3/S4/S5/S6 use half
//     the block; co-resident blocks fill the SIMDs.

typedef unsigned int  u32;
typedef unsigned short u16;

#define XR  136   // u16 per X row (272 B; row-start bank 4l%32 -> b128 conflict-free)
#define XR4 17    // uint4 per X row
#define YR  136   // u16 per y row
#define UR  136   // u16 per u row
#define SCR 68    // floats per sc row

typedef __attribute__((ext_vector_type(8))) __bf16 bf16x8;
typedef __attribute__((ext_vector_type(4))) float  f32x4;

struct __align__(16) Smem {
  u16   Xs[64 * XR];       // 17408 B bf16 X tile (rows>=len ZEROED)
  u16   u[8 * UR];         // 2176 B  bf16
  u16   y[8 * YR];         // 2176 B  bf16
  float q[128];            // 512 B
  float sc[8][SCR];        // 2176 B  scores -> attn (zeros at l>=len)
  float c[8];              // 32 B
  float ctx[128];          // 512 B
  int   isbf;
};                          // ~25 KB -> 4 blocks/CU (thread-capped)

__device__ __forceinline__ float blo(u32 u) { return __uint_as_float(u << 16); }
__device__ __forceinline__ float bhi(u32 u) { return __uint_as_float(u & 0xffff0000u); }
__device__ __forceinline__ float b2f(u16 u) { return __uint_as_float(((u32)u) << 16); }
__device__ __forceinline__ u16 f2b(float f) {
  union { __hip_bfloat16 h; u16 u; } cv; cv.h = __float2bfloat16(f); return cv.u;
}
__device__ __forceinline__ u32 pack2(float a, float b) {
  return (u32)f2b(a) | ((u32)f2b(b) << 16);
}

// 8 consecutive weight elems at element offset off -> bf16x8 fragment bits
template<bool BF>
__device__ __forceinline__ uint4 wfrag(const void* p, size_t off) {
  if (BF) {
    return *(const uint4*)((const u16*)p + off);
  } else {
    const float4* q4 = (const float4*)((const float*)p + off);
    float4 a = q4[0], b = q4[1];
    uint4 v;
    v.x = pack2(a.x, a.y); v.y = pack2(a.z, a.w);
    v.z = pack2(b.x, b.y); v.w = pack2(b.z, b.w);
    return v;
  }
}
template<bool BF>
__device__ __forceinline__ void load4(const void* p, size_t off, float* o) {
  if (BF) {
    uint2 v = *(const uint2*)((const u16*)p + off);
    o[0]=blo(v.x); o[1]=bhi(v.x); o[2]=blo(v.y); o[3]=bhi(v.y);
  } else {
    float4 v = *(const float4*)((const float*)p + off);
    o[0]=v.x; o[1]=v.y; o[2]=v.z; o[3]=v.w;
  }
}
template<bool BF>
__device__ __forceinline__ float lds1(const void* p, size_t off) {
  return BF ? b2f(((const u16*)p)[off]) : ((const float*)p)[off];
}

template<bool BF>
__device__ __forceinline__ void body(Smem& S, int b, int t,
    const void* inter, const int* lengths, const void* w_in, const void* b_in,
    const void* w_out, const void* b_out, void* out)
{
  const int len = lengths[b];
  const int lane = t & 63, w = t >> 6;

  // ---- S1: stage X (bf16); rows >= len get ZEROS (no HBM fetch) ----
#pragma unroll
  for (int r = 0; r < 2; ++r) {
    int g = t + 512 * r;                    // 0..1023 chunk ids
    int l = g >> 4, ci = g & 15;
    uint4 v = make_uint4(0u, 0u, 0u, 0u);
    if (l < len) {
      if (BF) {
        v = ((const uint4*)inter)[(size_t)b * 1024 + g];
      } else {
        const float4* src = (const float4*)inter + (size_t)b * 2048;
        float4 a = src[g * 2], bb = src[g * 2 + 1];
        v.x = pack2(a.x, a.y); v.y = pack2(a.z, a.w);
        v.z = pack2(bb.x, bb.y); v.w = pack2(bb.z, bb.w);
      }
    }
    ((uint4*)S.Xs)[l * XR4 + ci] = v;
  }
  __syncthreads();

  // ---- S2: q = Wq @ x0 + bq via MFMA, D = x0^T(1x128) @ Wq^T(128x128).
  //      Wave w -> e-tile w*16. A row0 = x0 (all lanes load row 0),
  //      B = Wq row e direct from global. Only D row 0 (acc[0]) is read.
  {
    const int e = w * 16 + (lane & 15);
    const int kb = (lane >> 4) * 8;
    f32x4 acc = {0.f, 0.f, 0.f, 0.f};
#pragma unroll
    for (int kc = 0; kc < 4; ++kc) {
      union { uint4 u4; bf16x8 b8; } A, Bf;
      A.u4  = *(const uint4*)&S.Xs[kc * 32 + kb];               // row 0
      Bf.u4 = wfrag<BF>(w_in, (size_t)e * 128 + kc * 32 + kb);
      acc = __builtin_amdgcn_mfma_f32_16x16x32_bf16(A.b8, Bf.b8, acc, 0, 0, 0);
    }
    if (lane < 16) S.q[e] = acc[0] + lds1<BF>(b_in, e);
  }
  __syncthreads();

  // ---- S3: u[h][j] = sum_d Wk[h16+d][j] q[h16+d]; c[h]  (256 thr) ----
  if (t < 256) {
    const int h = t >> 5, cc = t & 31;        // cols 4cc..4cc+3
    float a0=0.f,a1=0.f,a2=0.f,a3=0.f;
#pragma unroll
    for (int d = 0; d < 16; ++d) {
      float w4[4]; load4<BF>(w_in, (size_t)(128 + h * 16 + d) * 128 + cc * 4, w4);
      float q0 = S.q[h * 16 + d];
      a0 = fmaf(w4[0], q0, a0); a1 = fmaf(w4[1], q0, a1);
      a2 = fmaf(w4[2], q0, a2); a3 = fmaf(w4[3], q0, a3);
    }
    *(uint2*)&S.u[h * UR + cc * 4] = make_uint2(pack2(a0, a1), pack2(a2, a3));
    if (cc == 0) {
      float c0 = 0.f;
      for (int d = 0; d < 16; ++d)
        c0 += S.q[h * 16 + d] * lds1<BF>(b_in, 128 + h * 16 + d);
      S.c[h] = c0;
    }
  }
  __syncthreads();

  // ---- S4: scores via MFMA: scT[l][h] = X(64x128) @ u^T(128x8).
  //      Waves 0-3: l-tile mt=w (rows mt*16..+15). Waves 4-7 idle. ----
  if (w < 4) {
    const int mt = w;
    const int arow = mt * 16 + (lane & 15);
    const int col  = lane & 15;
    const int kb   = (lane >> 4) * 8;
    const bool hv  = (col < 8);
    f32x4 acc = {0.f, 0.f, 0.f, 0.f};
#pragma unroll
    for (int kc = 0; kc < 4; ++kc) {
      union { uint4 u4; bf16x8 b8; } a, bu;
      a.u4  = *(const uint4*)&S.Xs[arow * XR + kc * 32 + kb];
      bu.u4 = *(const uint4*)&S.u[(col & 7) * UR + kc * 32 + kb];
      if (!hv) bu.u4 = make_uint4(0u, 0u, 0u, 0u);
      acc = __builtin_amdgcn_mfma_f32_16x16x32_bf16(a.b8, bu.b8, acc, 0, 0, 0);
    }
    if (hv) {
      const int l0 = mt * 16 + (lane >> 4) * 4;
      const float cadd = S.c[col];
      f32x4 o;
      o[0] = (acc[0] + cadd) * 0.25f;
      o[1] = (acc[1] + cadd) * 0.25f;
      o[2] = (acc[2] + cadd) * 0.25f;
      o[3] = (acc[3] + cadd) * 0.25f;
      *(f32x4*)&S.sc[col][l0] = o;
    }
  }
  __syncthreads();

  // ---- S5: masked softmax in place; zeros written at l>=len (256 thr) ----
  if (t < 256) {
    const int h = t >> 5, sub = t & 31;
    const int l0 = sub, l1 = sub + 32;
    float s0 = S.sc[h][l0], s1 = S.sc[h][l1];
    const bool v0 = l0 < len, v1 = l1 < len;
    float m = fmaxf(v0 ? s0 : -INFINITY, v1 ? s1 : -INFINITY);
#pragma unroll
    for (int off = 16; off > 0; off >>= 1) m = fmaxf(m, __shfl_xor(m, off, 32));
    float e0 = v0 ? __expf(s0 - m) : 0.f;
    float e1 = v1 ? __expf(s1 - m) : 0.f;
    float s = e0 + e1;
#pragma unroll
    for (int off = 16; off > 0; off >>= 1) s += __shfl_xor(s, off, 32);
    float inv = 1.f / s;                       // len>=1 => s>0
    S.sc[h][l0] = e0 * inv;
    S.sc[h][l1] = e1 * inv;
  }
  __syncthreads();

  // ---- S6: y = P @ X via MFMA. Waves 0-3: j-pair w*32. Waves 4-7 idle.
  //      A = attn rows (f32->bf16; rows>=8 clamped, D rows>=8 unread).
  //      B = X column gather (u16); l>=len rows ZERO in both P and Xs. ----
  if (w < 4) {
    const int j0 = w * 32;
    const int hA = (lane & 15) < 8 ? (lane & 15) : 7;
    const int l8 = (lane >> 4) * 8;
    const int jc0 = j0 + (lane & 15), jc1 = jc0 + 16;
    f32x4 acc0 = {0.f,0.f,0.f,0.f}, acc1 = {0.f,0.f,0.f,0.f};
    const u16* xb = S.Xs;

    // kc = 0
    {
      const int lb = l8;
      float4 pa = *(const float4*)&S.sc[hA][lb];
      float4 pb = *(const float4*)&S.sc[hA][lb + 4];
      union { u32 u[4]; bf16x8 b; } A, B0, B1;
      A.u[0] = pack2(pa.x, pa.y); A.u[1] = pack2(pa.z, pa.w);
      A.u[2] = pack2(pb.x, pb.y); A.u[3] = pack2(pb.z, pb.w);
#pragma unroll
      for (int jj = 0; jj < 4; ++jj) {
        u32 lo0 = xb[(lb+2*jj)*XR + jc0], hi0 = xb[(lb+2*jj+1)*XR + jc0];
        u32 lo1 = xb[(lb+2*jj)*XR + jc1], hi1 = xb[(lb+2*jj+1)*XR + jc1];
        B0.u[jj] = lo0 | (hi0 << 16);
        B1.u[jj] = lo1 | (hi1 << 16);
      }
      acc0 = __builtin_amdgcn_mfma_f32_16x16x32_bf16(A.b, B0.b, acc0, 0, 0, 0);
      acc1 = __builtin_amdgcn_mfma_f32_16x16x32_bf16(A.b, B1.b, acc1, 0, 0, 0);
    }
    // kc = 1 only if len > 32 (wave-uniform)
    if (len > 32) {
      const int lb = 32 + l8;
      float4 pa = *(const float4*)&S.sc[hA][lb];
      float4 pb = *(const float4*)&S.sc[hA][lb + 4];
      union { u32 u[4]; bf16x8 b; } A, B0, B1;
      A.u[0] = pack2(pa.x, pa.y); A.u[1] = pack2(pa.z, pa.w);
      A.u[2] = pack2(pb.x, pb.y); A.u[3] = pack2(pb.z, pb.w);
#pragma unroll
      for (int jj = 0; jj < 4; ++jj) {
        u32 lo0 = xb[(lb+2*jj)*XR + jc0], hi0 = xb[(lb+2*jj+1)*XR + jc0];
        u32 lo1 = xb[(lb+2*jj)*XR + jc1], hi1 = xb[(lb+2*jj+1)*XR + jc1];
        B0.u[jj] = lo0 | (hi0 << 16);
        B1.u[jj] = lo1 | (hi1 << 16);
      }
      acc0 = __builtin_amdgcn_mfma_f32_16x16x32_bf16(A.b, B0.b, acc0, 0, 0, 0);
      acc1 = __builtin_amdgcn_mfma_f32_16x16x32_bf16(A.b, B1.b, acc1, 0, 0, 0);
    }
    // D: col=lane&15 (j in tile), row=(lane>>4)*4+r (h). Store h<8 only.
    const int rbase = (lane >> 4) * 4;
    if (rbase < 8) {
#pragma unroll
      for (int r = 0; r < 4; ++r) {
        S.y[(rbase + r) * YR + j0 + (lane & 15)]      = f2b(acc0[r]);
        S.y[(rbase + r) * YR + j0 + 16 + (lane & 15)] = f2b(acc1[r]);
      }
    }
  }
  __syncthreads();

  // ---- S7: ctx = Wv @ y_h + bv via MFMA; wave w = head w.
  //      A row0 = y_h (all lanes), B = Wv row e from global. ----
  {
    const int e = w * 16 + (lane & 15);           // head w slice
    const int kb = (lane >> 4) * 8;
    f32x4 acc = {0.f, 0.f, 0.f, 0.f};
#pragma unroll
    for (int kc = 0; kc < 4; ++kc) {
      union { uint4 u4; bf16x8 b8; } A, Bf;
      A.u4  = *(const uint4*)&S.y[w * YR + kc * 32 + kb];
      Bf.u4 = wfrag<BF>(w_in, (size_t)(256 + e) * 128 + kc * 32 + kb);
      acc = __builtin_amdgcn_mfma_f32_16x16x32_bf16(A.b8, Bf.b8, acc, 0, 0, 0);
    }
    if (lane < 16) S.ctx[e] = acc[0] + lds1<BF>(b_in, 256 + e);
  }
  __syncthreads();

  // ---- S8: out = Wout @ ctx + bout via MFMA; passthrough lanes 16-31 ----
  {
    const int e = w * 16 + (lane & 15);
    const int kb = (lane >> 4) * 8;
    f32x4 acc = {0.f, 0.f, 0.f, 0.f};
#pragma unroll
    for (int kc = 0; kc < 4; ++kc) {
      union { u32 u[4]; bf16x8 b; } A;
      union { uint4 u4; bf16x8 b8; } Bf;
      float4 ca = *(const float4*)&S.ctx[kc * 32 + kb];
      float4 cb = *(const float4*)&S.ctx[kc * 32 + kb + 4];
      A.u[0] = pack2(ca.x, ca.y); A.u[1] = pack2(ca.z, ca.w);
      A.u[2] = pack2(cb.x, cb.y); A.u[3] = pack2(cb.z, cb.w);
      Bf.u4 = wfrag<BF>(w_out, (size_t)e * 128 + kc * 32 + kb);
      acc = __builtin_amdgcn_mfma_f32_16x16x32_bf16(A.b, Bf.b8, acc, 0, 0, 0);
    }
    if (lane < 16) {
      float a0 = acc[0] + lds1<BF>(b_out, e);
      if (BF) ((u16*)out)[(size_t)b * 128 + e]   = f2b(a0);
      else    ((float*)out)[(size_t)b * 128 + e] = a0;
    } else if (lane < 32) {
      // query_info passthrough (bf16-rounded; well within threshold)
      size_t o1 = (size_t)8192 * 128 + (size_t)b * 128 + e;
      u16 xv = S.Xs[e];                          // row 0 always staged (len>=1)
      if (BF) ((u16*)out)[o1] = xv;
      else    ((float*)out)[o1] = b2f(xv);
    }
  }
}

__global__ __launch_bounds__(512, 4) void infoattn_kernel(
    const void* inter, const int* __restrict__ lengths,
    const void* w_in, const void* b_in, const void* w_out, const void* b_out,
    void* out)
{
  __shared__ Smem S;
  const int t = threadIdx.x;
  const int b = blockIdx.x;

  // ---- runtime dtype probe (uniform across all blocks) ----
  if (t < 64) {
    float v = b2f(((const u16*)inter)[t]);
    bool bad = !(fabsf(v) < 1000.f);
    unsigned long long m = __ballot(bad);
    if (t == 0) S.isbf = (m == 0ull) ? 1 : 0;
  }
  __syncthreads();
  const bool isbf = (S.isbf != 0);

  if (isbf) body<true >(S, b, t, inter, lengths, w_in, b_in, w_out, b_out, out);
  else      body<false>(S, b, t, inter, lengths, w_in, b_in, w_out, b_out, out);
}

extern "C" void kernel_launch(void* const* d_in, const int* in_sizes, int n_in,
                              void* d_out, int out_size, void* d_ws, size_t ws_size,
                              hipStream_t stream) {
  infoattn_kernel<<<dim3(8192), dim3(512), 0, stream>>>(
      d_in[0], (const int*)d_in[1], d_in[2], d_in[3], d_in[4], d_in[5], d_out);
}

// Round 7
// 380.828 us; speedup vs baseline: 1.3930x; 1.3930x over previous
//
#include <hip/hip_runtime.h>
#include <hip/hip_bf16.h>

// InfoMultiAttn: B=8192, L=64, E=128, H=8, HD=16. fp32 accumulate.
// Algebraic restructure:
//   scores[h,l] = (u_h . x_l + c_h)/4,  u_h = Wk_h^T q_h,  c_h = q_h . bk_h
//   ctx_h       = Wv_h y_h + bv_h,      y_h = sum_l attn[h,l] x_l
// History: R5 single-kernel (NB=2, all-MFMA) = 164.8us; R6 NB=1 regressed
// (263us: weight phases doubled, occupancy unchanged ~44%). Diagnosis: 9-phase
// serial chain with per-block L2 weight-load latency dominates; all pipes <25%.
// R11: 3-kernel split via d_ws (stream-ordered):
//   K1: q/u/c for all batches (weights amortized over 8-batch tiles).
//   K2: attention core only (stage X+u,c -> scores -> softmax -> y -> flush).
//       ZERO weight loads, 5 phases. S4/S5/S6 are R5-verbatim (verified).
//   K3: ctx+out as batched MFMA GEMMs over 16-batch tiles.
// Fallback: ws too small -> R5 mono kernel (proven 164.8us).

typedef unsigned int  u32;
typedef unsigned short u16;
typedef unsigned long long u64;

#define XR  136   // u16 per X row (272 B stride; b128 reads conflict-free)
#define XR4 17    // uint4 per X row
#define YR  136   // u16 per y row
#define UR  136   // u16 per u row
#define SCR 68    // floats per sc row
#define QR  132   // f32 per K1 q row (132%32=4 -> bank spread)
#define YSR 1032  // u16 per K3 y-stage row (2064B stride -> bank spread)

// workspace layout (bytes)
#define WS_U_OFF 0u          // u16 U[8192][1024]
#define WS_C_OFF 16777216u   // f32 c[8192][8]
#define WS_Y_OFF 17825792u   // u16 y[8192][1024]
#define WS_NEED  34603008u

typedef __attribute__((ext_vector_type(8))) __bf16 bf16x8;
typedef __attribute__((ext_vector_type(4))) float  f32x4;

__device__ __forceinline__ float blo(u32 u) { return __uint_as_float(u << 16); }
__device__ __forceinline__ float bhi(u32 u) { return __uint_as_float(u & 0xffff0000u); }
__device__ __forceinline__ float b2f(u16 u) { return __uint_as_float(((u32)u) << 16); }
__device__ __forceinline__ u16 f2b(float f) {
  union { __hip_bfloat16 h; u16 u; } cv; cv.h = __float2bfloat16(f); return cv.u;
}
__device__ __forceinline__ u32 pack2(float a, float b) {
  return (u32)f2b(a) | ((u32)f2b(b) << 16);
}

// 8 consecutive weight elems at element offset off -> bf16x8 fragment bits
template<bool BF>
__device__ __forceinline__ uint4 wfrag(const void* p, size_t off) {
  if (BF) {
    return *(const uint4*)((const u16*)p + off);
  } else {
    const float4* q4 = (const float4*)((const float*)p + off);
    float4 a = q4[0], b = q4[1];
    uint4 v;
    v.x = pack2(a.x, a.y); v.y = pack2(a.z, a.w);
    v.z = pack2(b.x, b.y); v.w = pack2(b.z, b.w);
    return v;
  }
}
template<bool BF>
__device__ __forceinline__ void load4(const void* p, size_t off, float* o) {
  if (BF) {
    uint2 v = *(const uint2*)((const u16*)p + off);
    o[0]=blo(v.x); o[1]=bhi(v.x); o[2]=blo(v.y); o[3]=bhi(v.y);
  } else {
    float4 v = *(const float4*)((const float*)p + off);
    o[0]=v.x; o[1]=v.y; o[2]=v.z; o[3]=v.w;
  }
}
template<bool BF>
__device__ __forceinline__ float lds1(const void* p, size_t off) {
  return BF ? b2f(((const u16*)p)[off]) : ((const float*)p)[off];
}

// ===================== K1: q -> U, c for all batches =====================
struct __align__(16) SmemK1 {
  u16   X0s[8 * XR];     // 2176 B (row 0 of 8 batches)
  float q[8 * QR];       // 4224 B
  int   isbf;
};

template<bool BF>
__device__ __forceinline__ void k1_body(SmemK1& S, int b0, int t,
    const void* inter, const void* w_in, const void* b_in,
    u16* Uws, float* Cws)
{
  const int lane = t & 63, w = t >> 6;

  // stage X0 (row l=0 of each batch; always valid since len>=1)
  if (t < 128) {
    const int i = t >> 4, ci = t & 15;
    const size_t bidx = (size_t)(b0 + i);
    uint4 v;
    if (BF) {
      v = ((const uint4*)inter)[bidx * 1024 + ci];
    } else {
      const float4* src = (const float4*)inter + bidx * 2048 + ci * 2;
      float4 a = src[0], b = src[1];
      v.x = pack2(a.x, a.y); v.y = pack2(a.z, a.w);
      v.z = pack2(b.x, b.y); v.w = pack2(b.z, b.w);
    }
    *(uint4*)&S.X0s[i * XR + ci * 8] = v;
  }
  __syncthreads();

  // Q = X0 @ Wq^T + bq via MFMA (A row=batch (rows>=8 garbage, D unread),
  // B = Wq row e from global; wave w -> e-tile w). Also c[b][w] = q_w . bk_w.
  {
    const int r15 = lane & 15, e = w * 16 + r15;
    const int kb = (lane >> 4) * 8, rbase = (lane >> 4) * 4;
    f32x4 acc = {0.f, 0.f, 0.f, 0.f};
#pragma unroll
    for (int kc = 0; kc < 4; ++kc) {
      union { uint4 u4; bf16x8 b8; } A, Bf;
      A.u4  = *(const uint4*)&S.X0s[(r15 & 7) * XR + kc * 32 + kb];
      Bf.u4 = wfrag<BF>(w_in, (size_t)e * 128 + kc * 32 + kb);
      acc = __builtin_amdgcn_mfma_f32_16x16x32_bf16(A.b8, Bf.b8, acc, 0, 0, 0);
    }
    const float bq  = lds1<BF>(b_in, e);
    const float bkv = lds1<BF>(b_in, 128 + e);   // bk[head w][dim r15]
    float cs[4];
#pragma unroll
    for (int r = 0; r < 4; ++r) {
      float qv = acc[r] + bq;
      if (rbase < 8) S.q[(rbase + r) * QR + e] = qv;   // D row=batch (0..7 valid)
      cs[r] = qv * bkv;
    }
#pragma unroll
    for (int off = 1; off < 16; off <<= 1) {
      cs[0] += __shfl_xor(cs[0], off, 64);
      cs[1] += __shfl_xor(cs[1], off, 64);
      cs[2] += __shfl_xor(cs[2], off, 64);
      cs[3] += __shfl_xor(cs[3], off, 64);
    }
    if (r15 == 0 && rbase < 8) {
#pragma unroll
      for (int r = 0; r < 4; ++r)
        Cws[(size_t)(b0 + rbase + r) * 8 + w] = cs[r];
    }
  }
  __syncthreads();

  // U[h][j] = sum_d q[h16+d] Wk[h16+d][j]; thread = (hh, bt, cc), 4 h each
  {
    const int hh = t >> 8, bt = (t >> 5) & 7, cc = t & 31;
#pragma unroll
    for (int hi = 0; hi < 4; ++hi) {
      const int h = hh * 4 + hi;
      float a0 = 0.f, a1 = 0.f, a2 = 0.f, a3 = 0.f;
#pragma unroll
      for (int d = 0; d < 16; ++d) {
        float w4[4]; load4<BF>(w_in, (size_t)(128 + h * 16 + d) * 128 + cc * 4, w4);
        float q0 = S.q[bt * QR + h * 16 + d];
        a0 = fmaf(w4[0], q0, a0); a1 = fmaf(w4[1], q0, a1);
        a2 = fmaf(w4[2], q0, a2); a3 = fmaf(w4[3], q0, a3);
      }
      *(uint2*)&Uws[(size_t)(b0 + bt) * 1024 + h * 128 + cc * 4] =
          make_uint2(pack2(a0, a1), pack2(a2, a3));
    }
  }
}

__global__ __launch_bounds__(512, 4) void k1_kernel(
    const void* inter, const void* w_in, const void* b_in,
    u16* Uws, float* Cws)
{
  __shared__ SmemK1 S;
  const int t = threadIdx.x;
  const int b0 = blockIdx.x * 8;
  if (t < 64) {
    float v = b2f(((const u16*)inter)[t]);
    bool bad = !(fabsf(v) < 1000.f);
    u64 m = __ballot(bad);
    if (t == 0) S.isbf = (m == 0ull) ? 1 : 0;
  }
  __syncthreads();
  if (S.isbf) k1_body<true >(S, b0, t, inter, w_in, b_in, Uws, Cws);
  else        k1_body<false>(S, b0, t, inter, w_in, b_in, Uws, Cws);
}

// ===================== K2: attention core (no weights) =====================
struct __align__(16) SmemK2 {
  u16   Xs[2][64 * XR];    // 34816 B (rows>=len ZEROED)
  u16   u[2][8 * UR];      // 4352 B
  u16   y[2][8 * YR];      // 4352 B
  float sc[2][8][SCR];     // 4352 B (zeros at l>=len after softmax)
  float c[2][8];           // 64 B
  int   isbf;
};                          // ~48 KB -> 3 blocks/CU

template<bool BF>
__device__ __forceinline__ void k2_body(SmemK2& S, int b0, int t,
    const void* inter, const int* lengths, const u16* Uws, const float* Cws,
    u16* Yws, void* out)
{
  const int len0 = lengths[b0];
  const int len1 = lengths[b0 + 1];
  const int lane = t & 63, w = t >> 6;

  // ---- S1: stage X (zero-fill rows>=len) + stage u,c from ws ----
#pragma unroll
  for (int r = 0; r < 4; ++r) {
    int g = t + 512 * r;
    int tile = g >> 10, gg = g & 1023, l = gg >> 4, ci = gg & 15;
    uint4 v = make_uint4(0u, 0u, 0u, 0u);
    if (l < (tile ? len1 : len0)) {
      if (BF) {
        v = ((const uint4*)inter)[(size_t)b0 * 1024 + g];
      } else {
        const float4* src = (const float4*)inter + (size_t)b0 * 2048;
        float4 a = src[g * 2], bb = src[g * 2 + 1];
        v.x = pack2(a.x, a.y); v.y = pack2(a.z, a.w);
        v.z = pack2(bb.x, bb.y); v.w = pack2(bb.z, bb.w);
      }
    }
    ((uint4*)S.Xs[tile])[l * XR4 + ci] = v;
  }
  if (t < 256) {
    const int bt = t >> 7, rem = t & 127, h = rem >> 4, ci = rem & 15;
    uint4 v = ((const uint4*)Uws)[(size_t)(b0 + bt) * 128 + h * 16 + ci];
    *(uint4*)&S.u[bt][h * UR + ci * 8] = v;
  } else if (t < 272) {
    const int i = t - 256, bt = i >> 3, h = i & 7;
    S.c[bt][h] = Cws[(size_t)(b0 + bt) * 8 + h];
  }
  __syncthreads();

  // ---- S4: scores via MFMA (R5-verified): scT = X @ u^T ----
  {
    const int bt = w >> 2, mt = w & 3;
    const int arow = mt * 16 + (lane & 15);
    const int col  = lane & 15;
    const int kb   = (lane >> 4) * 8;
    const bool hv  = (col < 8);
    f32x4 acc = {0.f, 0.f, 0.f, 0.f};
#pragma unroll
    for (int kc = 0; kc < 4; ++kc) {
      union { uint4 u4; bf16x8 b8; } a, bu;
      a.u4  = *(const uint4*)&S.Xs[bt][arow * XR + kc * 32 + kb];
      bu.u4 = *(const uint4*)&S.u[bt][(col & 7) * UR + kc * 32 + kb];
      if (!hv) bu.u4 = make_uint4(0u, 0u, 0u, 0u);
      acc = __builtin_amdgcn_mfma_f32_16x16x32_bf16(a.b8, bu.b8, acc, 0, 0, 0);
    }
    if (hv) {
      const int l0 = mt * 16 + (lane >> 4) * 4;
      const float cadd = S.c[bt][col];
      f32x4 o;
      o[0] = (acc[0] + cadd) * 0.25f;
      o[1] = (acc[1] + cadd) * 0.25f;
      o[2] = (acc[2] + cadd) * 0.25f;
      o[3] = (acc[3] + cadd) * 0.25f;
      *(f32x4*)&S.sc[bt][col][l0] = o;
    }
  }
  __syncthreads();

  // ---- S5: masked softmax in place; zeros at l>=len ----
  {
    const int bt = t >> 8, h = (t >> 5) & 7, sub = t & 31;
    const int len = bt ? len1 : len0;
    const int l0 = sub, l1 = sub + 32;
    float s0 = S.sc[bt][h][l0], s1 = S.sc[bt][h][l1];
    const bool v0 = l0 < len, v1 = l1 < len;
    float m = fmaxf(v0 ? s0 : -INFINITY, v1 ? s1 : -INFINITY);
#pragma unroll
    for (int off = 16; off > 0; off >>= 1) m = fmaxf(m, __shfl_xor(m, off, 32));
    float e0 = v0 ? __expf(s0 - m) : 0.f;
    float e1 = v1 ? __expf(s1 - m) : 0.f;
    float s = e0 + e1;
#pragma unroll
    for (int off = 16; off > 0; off >>= 1) s += __shfl_xor(s, off, 32);
    float inv = 1.f / s;
    S.sc[bt][h][l0] = e0 * inv;
    S.sc[bt][h][l1] = e1 * inv;
  }
  __syncthreads();

  // ---- S6: y = P @ X via MFMA (R5-verified) ----
  {
    const int bt = w >> 2, j0 = (w & 3) * 32;
    const int hA = (lane & 15) < 8 ? (lane & 15) : 7;
    const int l8 = (lane >> 4) * 8;
    const int jc0 = j0 + (lane & 15), jc1 = jc0 + 16;
    const int len = bt ? len1 : len0;
    f32x4 acc0 = {0.f,0.f,0.f,0.f}, acc1 = {0.f,0.f,0.f,0.f};
    const u16* xb = S.Xs[bt];
    {
      const int lb = l8;
      float4 pa = *(const float4*)&S.sc[bt][hA][lb];
      float4 pb = *(const float4*)&S.sc[bt][hA][lb + 4];
      union { u32 u[4]; bf16x8 b; } A, B0, B1;
      A.u[0] = pack2(pa.x, pa.y); A.u[1] = pack2(pa.z, pa.w);
      A.u[2] = pack2(pb.x, pb.y); A.u[3] = pack2(pb.z, pb.w);
#pragma unroll
      for (int jj = 0; jj < 4; ++jj) {
        u32 lo0 = xb[(lb+2*jj)*XR + jc0], hi0 = xb[(lb+2*jj+1)*XR + jc0];
        u32 lo1 = xb[(lb+2*jj)*XR + jc1], hi1 = xb[(lb+2*jj+1)*XR + jc1];
        B0.u[jj] = lo0 | (hi0 << 16);
        B1.u[jj] = lo1 | (hi1 << 16);
      }
      acc0 = __builtin_amdgcn_mfma_f32_16x16x32_bf16(A.b, B0.b, acc0, 0, 0, 0);
      acc1 = __builtin_amdgcn_mfma_f32_16x16x32_bf16(A.b, B1.b, acc1, 0, 0, 0);
    }
    if (len > 32) {
      const int lb = 32 + l8;
      float4 pa = *(const float4*)&S.sc[bt][hA][lb];
      float4 pb = *(const float4*)&S.sc[bt][hA][lb + 4];
      union { u32 u[4]; bf16x8 b; } A, B0, B1;
      A.u[0] = pack2(pa.x, pa.y); A.u[1] = pack2(pa.z, pa.w);
      A.u[2] = pack2(pb.x, pb.y); A.u[3] = pack2(pb.z, pb.w);
#pragma unroll
      for (int jj = 0; jj < 4; ++jj) {
        u32 lo0 = xb[(lb+2*jj)*XR + jc0], hi0 = xb[(lb+2*jj+1)*XR + jc0];
        u32 lo1 = xb[(lb+2*jj)*XR + jc1], hi1 = xb[(lb+2*jj+1)*XR + jc1];
        B0.u[jj] = lo0 | (hi0 << 16);
        B1.u[jj] = lo1 | (hi1 << 16);
      }
      acc0 = __builtin_amdgcn_mfma_f32_16x16x32_bf16(A.b, B0.b, acc0, 0, 0, 0);
      acc1 = __builtin_amdgcn_mfma_f32_16x16x32_bf16(A.b, B1.b, acc1, 0, 0, 0);
    }
    const int rbase = (lane >> 4) * 4;
    if (rbase < 8) {
#pragma unroll
      for (int r = 0; r < 4; ++r) {
        S.y[bt][(rbase + r) * YR + j0 + (lane & 15)]      = f2b(acc0[r]);
        S.y[bt][(rbase + r) * YR + j0 + 16 + (lane & 15)] = f2b(acc1[r]);
      }
    }
  }
  __syncthreads();

  // ---- flush: y -> ws (coalesced), query passthrough -> out ----
  if (t < 256) {
    const int bt = t >> 7, rem = t & 127, h = rem >> 4, ci = rem & 15;
    uint4 v = *(const uint4*)&S.y[bt][h * YR + ci * 8];
    ((uint4*)Yws)[(size_t)(b0 + bt) * 128 + h * 16 + ci] = v;
  } else {
    const int i = t - 256, bt = i >> 7, e = i & 127;
    size_t o1 = (size_t)8192 * 128 + (size_t)(b0 + bt) * 128 + e;
    u16 xv = S.Xs[bt][e];                      // row 0 always staged (len>=1)
    if (BF) ((u16*)out)[o1] = xv;
    else    ((float*)out)[o1] = b2f(xv);
  }
}

__global__ __launch_bounds__(512, 4) void k2_kernel(
    const void* inter, const int* __restrict__ lengths,
    const u16* Uws, const float* Cws, u16* Yws, void* out)
{
  __shared__ SmemK2 S;
  const int t = threadIdx.x;
  const int b0 = blockIdx.x * 2;
  if (t < 64) {
    float v = b2f(((const u16*)inter)[t]);
    bool bad = !(fabsf(v) < 1000.f);
    u64 m = __ballot(bad);
    if (t == 0) S.isbf = (m == 0ull) ? 1 : 0;
  }
  __syncthreads();
  if (S.isbf) k2_body<true >(S, b0, t, inter, lengths, Uws, Cws, Yws, out);
  else        k2_body<false>(S, b0, t, inter, lengths, Uws, Cws, Yws, out);
}

// ===================== K3: ctx + out batched GEMMs =====================
struct __align__(16) SmemK3 {
  u16 ys[16 * YSR];    // 33024 B
  u16 ctx[16 * 136];   // 4352 B
  int isbf;
};

template<bool BF>
__device__ __forceinline__ void k3_body(SmemK3& S, int b0, int t,
    const u16* Yws, const void* w_in, const void* b_in,
    const void* w_out, const void* b_out, void* out)
{
  const int lane = t & 63, w = t >> 6;

  // stage y tile (16 batches x 1024 bf16, fully coalesced)
#pragma unroll
  for (int r = 0; r < 4; ++r) {
    int idx = t + 512 * r;                 // 0..2047
    int row = idx >> 7, ci = idx & 127;
    uint4 v = ((const uint4*)Yws)[(size_t)(b0 + row) * 128 + ci];
    *(uint4*)&S.ys[row * YSR + ci * 8] = v;
  }
  __syncthreads();

  // ctx tile: head ct = w. D[b,j] = sum_k y[b][ct*128+k] * Wv[ct16+j][k]
  {
    const int col = lane & 15, kb = (lane >> 4) * 8, rbase = (lane >> 4) * 4;
    f32x4 acc = {0.f, 0.f, 0.f, 0.f};
#pragma unroll
    for (int kc = 0; kc < 4; ++kc) {
      union { uint4 u4; bf16x8 b8; } A, Bf;
      A.u4  = *(const uint4*)&S.ys[col * YSR + w * 128 + kc * 32 + kb];
      Bf.u4 = wfrag<BF>(w_in, (size_t)(256 + w * 16 + col) * 128 + kc * 32 + kb);
      acc = __builtin_amdgcn_mfma_f32_16x16x32_bf16(A.b8, Bf.b8, acc, 0, 0, 0);
    }
    const float bv = lds1<BF>(b_in, 256 + w * 16 + col);
#pragma unroll
    for (int r = 0; r < 4; ++r)
      S.ctx[(rbase + r) * 136 + w * 16 + col] = f2b(acc[r] + bv);
  }
  __syncthreads();

  // out tile: e-tile w. D[b,e] = sum_k ctx[b,k] * Wout[e][k]
  {
    const int col = lane & 15, kb = (lane >> 4) * 8, rbase = (lane >> 4) * 4;
    f32x4 acc = {0.f, 0.f, 0.f, 0.f};
#pragma unroll
    for (int kc = 0; kc < 4; ++kc) {
      union { uint4 u4; bf16x8 b8; } A, Bf;
      A.u4  = *(const uint4*)&S.ctx[col * 136 + kc * 32 + kb];
      Bf.u4 = wfrag<BF>(w_out, (size_t)(w * 16 + col) * 128 + kc * 32 + kb);
      acc = __builtin_amdgcn_mfma_f32_16x16x32_bf16(A.b8, Bf.b8, acc, 0, 0, 0);
    }
    const float bo = lds1<BF>(b_out, w * 16 + col);
#pragma unroll
    for (int r = 0; r < 4; ++r) {
      float v = acc[r] + bo;
      size_t oo = (size_t)(b0 + rbase + r) * 128 + w * 16 + col;
      if (BF) ((u16*)out)[oo] = f2b(v);
      else    ((float*)out)[oo] = v;
    }
  }
}

__global__ __launch_bounds__(512, 4) void k3_kernel(
    const u16* Yws, const void* w_in, const void* b_in,
    const void* w_out, const void* b_out, void* out)
{
  __shared__ SmemK3 S;
  const int t = threadIdx.x;
  const int b0 = blockIdx.x * 16;
  if (t < 64) {   // probe weight dtype on w_out (nonzero uniform values)
    float v = b2f(((const u16*)w_out)[t]);
    bool bad = !(fabsf(v) < 1000.f);
    u64 m = __ballot(bad);
    if (t == 0) S.isbf = (m == 0ull) ? 1 : 0;
  }
  __syncthreads();
  if (S.isbf) k3_body<true >(S, b0, t, Yws, w_in, b_in, w_out, b_out, out);
  else        k3_body<false>(S, b0, t, Yws, w_in, b_in, w_out, b_out, out);
}

// ===================== mono fallback (R5, proven 164.8us) =====================
struct __align__(16) SmemM {
  u16   Xs[2][64 * XR];
  u16   u[2][8 * UR];
  u16   y[2][8 * YR];
  float q[2][128];
  float sc[2][8][SCR];
  float c[2][8];
  float ctx[2][128];
  int   isbf;
};

template<bool BF>
__device__ __forceinline__ void mono_body(SmemM& S, int b0, int t,
    const void* inter, const int* lengths, const void* w_in, const void* b_in,
    const void* w_out, const void* b_out, void* out)
{
  const int len0 = lengths[b0];
  const int len1 = lengths[b0 + 1];
  const int lane = t & 63, w = t >> 6;

#pragma unroll
  for (int r = 0; r < 4; ++r) {
    int g = t + 512 * r;
    int tile = g >> 10, gg = g & 1023, l = gg >> 4, ci = gg & 15;
    uint4 v = make_uint4(0u, 0u, 0u, 0u);
    if (l < (tile ? len1 : len0)) {
      if (BF) {
        v = ((const uint4*)inter)[(size_t)b0 * 1024 + g];
      } else {
        const float4* src = (const float4*)inter + (size_t)b0 * 2048;
        float4 a = src[g * 2], b = src[g * 2 + 1];
        v.x = pack2(a.x, a.y); v.y = pack2(a.z, a.w);
        v.z = pack2(b.x, b.y); v.w = pack2(b.z, b.w);
      }
    }
    ((uint4*)S.Xs[tile])[l * XR4 + ci] = v;
  }
  __syncthreads();

  {
    const int e = w * 16 + (lane & 15);
    const int btc = (lane & 15) < 2 ? (lane & 15) : 1;
    const int kb = (lane >> 4) * 8;
    f32x4 acc = {0.f, 0.f, 0.f, 0.f};
#pragma unroll
    for (int kc = 0; kc < 4; ++kc) {
      union { uint4 u4; bf16x8 b8; } A, Bf;
      A.u4  = *(const uint4*)&S.Xs[btc][kc * 32 + kb];
      Bf.u4 = wfrag<BF>(w_in, (size_t)e * 128 + kc * 32 + kb);
      acc = __builtin_amdgcn_mfma_f32_16x16x32_bf16(A.b8, Bf.b8, acc, 0, 0, 0);
    }
    if (lane < 16) {
      float bq = lds1<BF>(b_in, e);
      S.q[0][e] = acc[0] + bq;
      S.q[1][e] = acc[1] + bq;
    }
  }
  __syncthreads();

  {
    const int bt = t >> 8, h = (t >> 5) & 7, cc = t & 31;
    float a0=0.f,a1=0.f,a2=0.f,a3=0.f;
#pragma unroll
    for (int d = 0; d < 16; ++d) {
      float w4[4]; load4<BF>(w_in, (size_t)(128 + h * 16 + d) * 128 + cc * 4, w4);
      float q0 = S.q[bt][h * 16 + d];
      a0 = fmaf(w4[0], q0, a0); a1 = fmaf(w4[1], q0, a1);
      a2 = fmaf(w4[2], q0, a2); a3 = fmaf(w4[3], q0, a3);
    }
    *(uint2*)&S.u[bt][h * UR + cc * 4] = make_uint2(pack2(a0, a1), pack2(a2, a3));
    if (cc == 0) {
      float c0 = 0.f;
      for (int d = 0; d < 16; ++d)
        c0 += S.q[bt][h * 16 + d] * lds1<BF>(b_in, 128 + h * 16 + d);
      S.c[bt][h] = c0;
    }
  }
  __syncthreads();

  {
    const int bt = w >> 2, mt = w & 3;
    const int arow = mt * 16 + (lane & 15);
    const int col  = lane & 15;
    const int kb   = (lane >> 4) * 8;
    const bool hv  = (col < 8);
    f32x4 acc = {0.f, 0.f, 0.f, 0.f};
#pragma unroll
    for (int kc = 0; kc < 4; ++kc) {
      union { uint4 u4; bf16x8 b8; } a, bu;
      a.u4  = *(const uint4*)&S.Xs[bt][arow * XR + kc * 32 + kb];
      bu.u4 = *(const uint4*)&S.u[bt][(col & 7) * UR + kc * 32 + kb];
      if (!hv) bu.u4 = make_uint4(0u, 0u, 0u, 0u);
      acc = __builtin_amdgcn_mfma_f32_16x16x32_bf16(a.b8, bu.b8, acc, 0, 0, 0);
    }
    if (hv) {
      const int l0 = mt * 16 + (lane >> 4) * 4;
      const float cadd = S.c[bt][col];
      f32x4 o;
      o[0] = (acc[0] + cadd) * 0.25f;
      o[1] = (acc[1] + cadd) * 0.25f;
      o[2] = (acc[2] + cadd) * 0.25f;
      o[3] = (acc[3] + cadd) * 0.25f;
      *(f32x4*)&S.sc[bt][col][l0] = o;
    }
  }
  __syncthreads();

  {
    const int bt = t >> 8, h = (t >> 5) & 7, sub = t & 31;
    const int len = bt ? len1 : len0;
    const int l0 = sub, l1 = sub + 32;
    float s0 = S.sc[bt][h][l0], s1 = S.sc[bt][h][l1];
    const bool v0 = l0 < len, v1 = l1 < len;
    float m = fmaxf(v0 ? s0 : -INFINITY, v1 ? s1 : -INFINITY);
#pragma unroll
    for (int off = 16; off > 0; off >>= 1) m = fmaxf(m, __shfl_xor(m, off, 32));
    float e0 = v0 ? __expf(s0 - m) : 0.f;
    float e1 = v1 ? __expf(s1 - m) : 0.f;
    float s = e0 + e1;
#pragma unroll
    for (int off = 16; off > 0; off >>= 1) s += __shfl_xor(s, off, 32);
    float inv = 1.f / s;
    S.sc[bt][h][l0] = e0 * inv;
    S.sc[bt][h][l1] = e1 * inv;
  }
  __syncthreads();

  {
    const int bt = w >> 2, j0 = (w & 3) * 32;
    const int hA = (lane & 15) < 8 ? (lane & 15) : 7;
    const int l8 = (lane >> 4) * 8;
    const int jc0 = j0 + (lane & 15), jc1 = jc0 + 16;
    const int len = bt ? len1 : len0;
    f32x4 acc0 = {0.f,0.f,0.f,0.f}, acc1 = {0.f,0.f,0.f,0.f};
    const u16* xb = S.Xs[bt];
    {
      const int lb = l8;
      float4 pa = *(const float4*)&S.sc[bt][hA][lb];
      float4 pb = *(const float4*)&S.sc[bt][hA][lb + 4];
      union { u32 u[4]; bf16x8 b; } A, B0, B1;
      A.u[0] = pack2(pa.x, pa.y); A.u[1] = pack2(pa.z, pa.w);
      A.u[2] = pack2(pb.x, pb.y); A.u[3] = pack2(pb.z, pb.w);
#pragma unroll
      for (int jj = 0; jj < 4; ++jj) {
        u32 lo0 = xb[(lb+2*jj)*XR + jc0], hi0 = xb[(lb+2*jj+1)*XR + jc0];
        u32 lo1 = xb[(lb+2*jj)*XR + jc1], hi1 = xb[(lb+2*jj+1)*XR + jc1];
        B0.u[jj] = lo0 | (hi0 << 16);
        B1.u[jj] = lo1 | (hi1 << 16);
      }
      acc0 = __builtin_amdgcn_mfma_f32_16x16x32_bf16(A.b, B0.b, acc0, 0, 0, 0);
      acc1 = __builtin_amdgcn_mfma_f32_16x16x32_bf16(A.b, B1.b, acc1, 0, 0, 0);
    }
    if (len > 32) {
      const int lb = 32 + l8;
      float4 pa = *(const float4*)&S.sc[bt][hA][lb];
      float4 pb = *(const float4*)&S.sc[bt][hA][lb + 4];
      union { u32 u[4]; bf16x8 b; } A, B0, B1;
      A.u[0] = pack2(pa.x, pa.y); A.u[1] = pack2(pa.z, pa.w);
      A.u[2] = pack2(pb.x, pb.y); A.u[3] = pack2(pb.z, pb.w);
#pragma unroll
      for (int jj = 0; jj < 4; ++jj) {
        u32 lo0 = xb[(lb+2*jj)*XR + jc0], hi0 = xb[(lb+2*jj+1)*XR + jc0];
        u32 lo1 = xb[(lb+2*jj)*XR + jc1], hi1 = xb[(lb+2*jj+1)*XR + jc1];
        B0.u[jj] = lo0 | (hi0 << 16);
        B1.u[jj] = lo1 | (hi1 << 16);
      }
      acc0 = __builtin_amdgcn_mfma_f32_16x16x32_bf16(A.b, B0.b, acc0, 0, 0, 0);
      acc1 = __builtin_amdgcn_mfma_f32_16x16x32_bf16(A.b, B1.b, acc1, 0, 0, 0);
    }
    const int rbase = (lane >> 4) * 4;
    if (rbase < 8) {
#pragma unroll
      for (int r = 0; r < 4; ++r) {
        S.y[bt][(rbase + r) * YR + j0 + (lane & 15)]      = f2b(acc0[r]);
        S.y[bt][(rbase + r) * YR + j0 + 16 + (lane & 15)] = f2b(acc1[r]);
      }
    }
  }
  __syncthreads();

  {
    const int e = w * 16 + (lane & 15);
    const int btc = (lane & 15) < 2 ? (lane & 15) : 1;
    const int kb = (lane >> 4) * 8;
    f32x4 acc = {0.f, 0.f, 0.f, 0.f};
#pragma unroll
    for (int kc = 0; kc < 4; ++kc) {
      union { uint4 u4; bf16x8 b8; } A, Bf;
      A.u4  = *(const uint4*)&S.y[btc][w * YR + kc * 32 + kb];
      Bf.u4 = wfrag<BF>(w_in, (size_t)(256 + e) * 128 + kc * 32 + kb);
      acc = __builtin_amdgcn_mfma_f32_16x16x32_bf16(A.b8, Bf.b8, acc, 0, 0, 0);
    }
    if (lane < 16) {
      S.ctx[0][e] = acc[0] + lds1<BF>(b_in, 256 + e);
      S.ctx[1][e] = acc[1] + lds1<BF>(b_in, 256 + e);
    }
  }
  __syncthreads();

  {
    const int e = w * 16 + (lane & 15);
    const int btc = (lane & 15) < 2 ? (lane & 15) : 1;
    const int kb = (lane >> 4) * 8;
    f32x4 acc = {0.f, 0.f, 0.f, 0.f};
#pragma unroll
    for (int kc = 0; kc < 4; ++kc) {
      union { u32 u[4]; bf16x8 b; } A;
      union { uint4 u4; bf16x8 b8; } Bf;
      float4 ca = *(const float4*)&S.ctx[btc][kc * 32 + kb];
      float4 cb = *(const float4*)&S.ctx[btc][kc * 32 + kb + 4];
      A.u[0] = pack2(ca.x, ca.y); A.u[1] = pack2(ca.z, ca.w);
      A.u[2] = pack2(cb.x, cb.y); A.u[3] = pack2(cb.z, cb.w);
      Bf.u4 = wfrag<BF>(w_out, (size_t)e * 128 + kc * 32 + kb);
      acc = __builtin_amdgcn_mfma_f32_16x16x32_bf16(A.b, Bf.b8, acc, 0, 0, 0);
    }
    if (lane < 16) {
      float bo = lds1<BF>(b_out, e);
      float a0 = acc[0] + bo, a1 = acc[1] + bo;
      if (BF) {
        ((u16*)out)[(size_t)b0 * 128 + e]       = f2b(a0);
        ((u16*)out)[(size_t)(b0 + 1) * 128 + e] = f2b(a1);
      } else {
        ((float*)out)[(size_t)b0 * 128 + e]       = a0;
        ((float*)out)[(size_t)(b0 + 1) * 128 + e] = a1;
      }
    } else if (lane < 48) {
      const int bt = (lane >> 4) - 1;
      size_t o1 = (size_t)8192 * 128 + (size_t)(b0 + bt) * 128 + e;
      u16 xv = S.Xs[bt][e];
      if (BF) ((u16*)out)[o1] = xv;
      else    ((float*)out)[o1] = b2f(xv);
    }
  }
}

__global__ __launch_bounds__(512, 4) void mono_kernel(
    const void* inter, const int* __restrict__ lengths,
    const void* w_in, const void* b_in, const void* w_out, const void* b_out,
    void* out)
{
  __shared__ SmemM S;
  const int t = threadIdx.x;
  const int b0 = blockIdx.x * 2;
  if (t < 64) {
    float v = b2f(((const u16*)inter)[t]);
    bool bad = !(fabsf(v) < 1000.f);
    u64 m = __ballot(bad);
    if (t == 0) S.isbf = (m == 0ull) ? 1 : 0;
  }
  __syncthreads();
  if (S.isbf) mono_body<true >(S, b0, t, inter, lengths, w_in, b_in, w_out, b_out, out);
  else        mono_body<false>(S, b0, t, inter, lengths, w_in, b_in, w_out, b_out, out);
}

extern "C" void kernel_launch(void* const* d_in, const int* in_sizes, int n_in,
                              void* d_out, int out_size, void* d_ws, size_t ws_size,
                              hipStream_t stream) {
  if (d_ws && ws_size >= (size_t)WS_NEED) {
    u16*   Uws = (u16*)((char*)d_ws + WS_U_OFF);
    float* Cws = (float*)((char*)d_ws + WS_C_OFF);
    u16*   Yws = (u16*)((char*)d_ws + WS_Y_OFF);
    k1_kernel<<<dim3(1024), dim3(512), 0, stream>>>(
        d_in[0], d_in[2], d_in[3], Uws, Cws);
    k2_kernel<<<dim3(4096), dim3(512), 0, stream>>>(
        d_in[0], (const int*)d_in[1], Uws, Cws, Yws, d_out);
    k3_kernel<<<dim3(512), dim3(512), 0, stream>>>(
        Yws, d_in[2], d_in[3], d_in[4], d_in[5], d_out);
  } else {
    mono_kernel<<<dim3(4096), dim3(512), 0, stream>>>(
        d_in[0], (const int*)d_in[1], d_in[2], d_in[3], d_in[4], d_in[5], d_out);
  }
}

// Round 8
// 372.195 us; speedup vs baseline: 1.4253x; 1.0232x over previous
//
#include <hip/hip_runtime.h>
#include <hip/hip_bf16.h>

// InfoMultiAttn: B=8192, L=64, E=128, H=8, HD=16. fp32 accumulate.
// Algebraic restructure:
//   scores[h,l] = (u_h . x_l + c_h)/4,  u_h = Wk_h^T q_h,  c_h = q_h . bk_h
//   ctx_h       = Wv_h y_h + bv_h,      y_h = sum_l attn[h,l] x_l
// R11 (380.8us harness, ~112us GPU): 3-kernel split via d_ws:
//   K1 q/u/c (weights amortized 8 batches) | K2 attention core (no weights)
//   | K3 ctx+out GEMMs (16-batch tiles). Mono fallback = R5 (164.8us).
// R12: K2 loses flush phase (S6 writes y regs->ws direct; passthrough moves
//   into S1 from staging regs — fp32 mode now exact) and gates S4 l-tiles by
//   len. K1 U-phase loops inverted (weights outer, batch inner): weight-load
//   instrs 32.8K -> 8.2K per block at same FMA count.

typedef unsigned int  u32;
typedef unsigned short u16;
typedef unsigned long long u64;

#define XR  136   // u16 per X row (272 B stride; b128 reads conflict-free)
#define XR4 17    // uint4 per X row
#define YR  136   // u16 per y row
#define UR  136   // u16 per u row
#define SCR 68    // floats per sc row
#define QR  132   // f32 per K1 q row (132%32=4 -> bank spread)
#define YSR 1032  // u16 per K3 y-stage row (2064B stride -> bank spread)

// workspace layout (bytes)
#define WS_U_OFF 0u          // u16 U[8192][1024]
#define WS_C_OFF 16777216u   // f32 c[8192][8]
#define WS_Y_OFF 17825792u   // u16 y[8192][1024]
#define WS_NEED  34603008u

typedef __attribute__((ext_vector_type(8))) __bf16 bf16x8;
typedef __attribute__((ext_vector_type(4))) float  f32x4;

__device__ __forceinline__ float blo(u32 u) { return __uint_as_float(u << 16); }
__device__ __forceinline__ float bhi(u32 u) { return __uint_as_float(u & 0xffff0000u); }
__device__ __forceinline__ float b2f(u16 u) { return __uint_as_float(((u32)u) << 16); }
__device__ __forceinline__ u16 f2b(float f) {
  union { __hip_bfloat16 h; u16 u; } cv; cv.h = __float2bfloat16(f); return cv.u;
}
__device__ __forceinline__ u32 pack2(float a, float b) {
  return (u32)f2b(a) | ((u32)f2b(b) << 16);
}

// 8 consecutive weight elems at element offset off -> bf16x8 fragment bits
template<bool BF>
__device__ __forceinline__ uint4 wfrag(const void* p, size_t off) {
  if (BF) {
    return *(const uint4*)((const u16*)p + off);
  } else {
    const float4* q4 = (const float4*)((const float*)p + off);
    float4 a = q4[0], b = q4[1];
    uint4 v;
    v.x = pack2(a.x, a.y); v.y = pack2(a.z, a.w);
    v.z = pack2(b.x, b.y); v.w = pack2(b.z, b.w);
    return v;
  }
}
template<bool BF>
__device__ __forceinline__ void load4(const void* p, size_t off, float* o) {
  if (BF) {
    uint2 v = *(const uint2*)((const u16*)p + off);
    o[0]=blo(v.x); o[1]=bhi(v.x); o[2]=blo(v.y); o[3]=bhi(v.y);
  } else {
    float4 v = *(const float4*)((const float*)p + off);
    o[0]=v.x; o[1]=v.y; o[2]=v.z; o[3]=v.w;
  }
}
template<bool BF>
__device__ __forceinline__ float lds1(const void* p, size_t off) {
  return BF ? b2f(((const u16*)p)[off]) : ((const float*)p)[off];
}

// ===================== K1: q -> U, c for all batches =====================
struct __align__(16) SmemK1 {
  u16   X0s[8 * XR];     // 2176 B (row 0 of 8 batches)
  float q[8 * QR];       // 4224 B
  int   isbf;
};

template<bool BF>
__device__ __forceinline__ void k1_body(SmemK1& S, int b0, int t,
    const void* inter, const void* w_in, const void* b_in,
    u16* Uws, float* Cws)
{
  const int lane = t & 63, w = t >> 6;

  // stage X0 (row l=0 of each batch; always valid since len>=1)
  if (t < 128) {
    const int i = t >> 4, ci = t & 15;
    const size_t bidx = (size_t)(b0 + i);
    uint4 v;
    if (BF) {
      v = ((const uint4*)inter)[bidx * 1024 + ci];
    } else {
      const float4* src = (const float4*)inter + bidx * 2048 + ci * 2;
      float4 a = src[0], b = src[1];
      v.x = pack2(a.x, a.y); v.y = pack2(a.z, a.w);
      v.z = pack2(b.x, b.y); v.w = pack2(b.z, b.w);
    }
    *(uint4*)&S.X0s[i * XR + ci * 8] = v;
  }
  __syncthreads();

  // Q = X0 @ Wq^T + bq via MFMA (A row=batch (rows>=8 garbage, D unread),
  // B = Wq row e from global; wave w -> e-tile w). Also c[b][w] = q_w . bk_w.
  {
    const int r15 = lane & 15, e = w * 16 + r15;
    const int kb = (lane >> 4) * 8, rbase = (lane >> 4) * 4;
    f32x4 acc = {0.f, 0.f, 0.f, 0.f};
#pragma unroll
    for (int kc = 0; kc < 4; ++kc) {
      union { uint4 u4; bf16x8 b8; } A, Bf;
      A.u4  = *(const uint4*)&S.X0s[(r15 & 7) * XR + kc * 32 + kb];
      Bf.u4 = wfrag<BF>(w_in, (size_t)e * 128 + kc * 32 + kb);
      acc = __builtin_amdgcn_mfma_f32_16x16x32_bf16(A.b8, Bf.b8, acc, 0, 0, 0);
    }
    const float bq  = lds1<BF>(b_in, e);
    const float bkv = lds1<BF>(b_in, 128 + e);   // bk[head w][dim r15]
    float cs[4];
#pragma unroll
    for (int r = 0; r < 4; ++r) {
      float qv = acc[r] + bq;
      if (rbase < 8) S.q[(rbase + r) * QR + e] = qv;   // D row=batch (0..7 valid)
      cs[r] = qv * bkv;
    }
#pragma unroll
    for (int off = 1; off < 16; off <<= 1) {
      cs[0] += __shfl_xor(cs[0], off, 64);
      cs[1] += __shfl_xor(cs[1], off, 64);
      cs[2] += __shfl_xor(cs[2], off, 64);
      cs[3] += __shfl_xor(cs[3], off, 64);
    }
    if (r15 == 0 && rbase < 8) {
#pragma unroll
      for (int r = 0; r < 4; ++r)
        Cws[(size_t)(b0 + rbase + r) * 8 + w] = cs[r];
    }
  }
  __syncthreads();

  // U[h][j] = sum_d q[h16+d] Wk[h16+d][j]; weights OUTER, batch INNER:
  // thread = (h: t>>6, cc: (t&63)>>1, s: t&1); s covers batches 4s..4s+3.
  // Weight load4 once per (h,d,cc), reused across 4 batches.
  {
    const int h = t >> 6, rem = t & 63;
    const int cc = rem >> 1, s = rem & 1;
    float a[4][4] = {{0.f,0.f,0.f,0.f},{0.f,0.f,0.f,0.f},
                     {0.f,0.f,0.f,0.f},{0.f,0.f,0.f,0.f}};
#pragma unroll
    for (int d = 0; d < 16; ++d) {
      float w4[4]; load4<BF>(w_in, (size_t)(128 + h * 16 + d) * 128 + cc * 4, w4);
#pragma unroll
      for (int bi = 0; bi < 4; ++bi) {
        float q0 = S.q[(s * 4 + bi) * QR + h * 16 + d];
        a[bi][0] = fmaf(w4[0], q0, a[bi][0]);
        a[bi][1] = fmaf(w4[1], q0, a[bi][1]);
        a[bi][2] = fmaf(w4[2], q0, a[bi][2]);
        a[bi][3] = fmaf(w4[3], q0, a[bi][3]);
      }
    }
#pragma unroll
    for (int bi = 0; bi < 4; ++bi) {
      const int bt = s * 4 + bi;
      *(uint2*)&Uws[(size_t)(b0 + bt) * 1024 + h * 128 + cc * 4] =
          make_uint2(pack2(a[bi][0], a[bi][1]), pack2(a[bi][2], a[bi][3]));
    }
  }
}

__global__ __launch_bounds__(512, 4) void k1_kernel(
    const void* inter, const void* w_in, const void* b_in,
    u16* Uws, float* Cws)
{
  __shared__ SmemK1 S;
  const int t = threadIdx.x;
  const int b0 = blockIdx.x * 8;
  if (t < 64) {
    float v = b2f(((const u16*)inter)[t]);
    bool bad = !(fabsf(v) < 1000.f);
    u64 m = __ballot(bad);
    if (t == 0) S.isbf = (m == 0ull) ? 1 : 0;
  }
  __syncthreads();
  if (S.isbf) k1_body<true >(S, b0, t, inter, w_in, b_in, Uws, Cws);
  else        k1_body<false>(S, b0, t, inter, w_in, b_in, Uws, Cws);
}

// ===================== K2: attention core (no weights) =====================
struct __align__(16) SmemK2 {
  u16   Xs[2][64 * XR];    // 34816 B (rows>=len ZEROED)
  u16   u[2][8 * UR];      // 4352 B
  float sc[2][8][SCR];     // 4352 B (zeros at l>=len after softmax)
  float c[2][8];           // 64 B
  int   isbf;
};                          // ~43.6 KB -> 3 blocks/CU

template<bool BF>
__device__ __forceinline__ void k2_body(SmemK2& S, int b0, int t,
    const void* inter, const int* lengths, const u16* Uws, const float* Cws,
    u16* Yws, void* out)
{
  const int len0 = lengths[b0];
  const int len1 = lengths[b0 + 1];
  const int lane = t & 63, w = t >> 6;

  // ---- S1: stage X (zero-fill rows>=len) + u,c from ws; the l==0 staging
  //      threads also emit the query-passthrough from their registers ----
#pragma unroll
  for (int r = 0; r < 4; ++r) {
    int g = t + 512 * r;
    int tile = g >> 10, gg = g & 1023, l = gg >> 4, ci = gg & 15;
    uint4 v = make_uint4(0u, 0u, 0u, 0u);
    if (l < (tile ? len1 : len0)) {
      if (BF) {
        v = ((const uint4*)inter)[(size_t)b0 * 1024 + g];
        if (l == 0)
          ((uint4*)out)[131072 + (size_t)(b0 + tile) * 16 + ci] = v;
      } else {
        const float4* src = (const float4*)inter + (size_t)b0 * 2048;
        float4 a = src[g * 2], bb = src[g * 2 + 1];
        if (l == 0) {
          float4* o4 = (float4*)out + 262144 + (size_t)(b0 + tile) * 32 + ci * 2;
          o4[0] = a; o4[1] = bb;                 // exact fp32 passthrough
        }
        v.x = pack2(a.x, a.y); v.y = pack2(a.z, a.w);
        v.z = pack2(bb.x, bb.y); v.w = pack2(bb.z, bb.w);
      }
    }
    ((uint4*)S.Xs[tile])[l * XR4 + ci] = v;
  }
  if (t < 256) {
    const int bt = t >> 7, rem = t & 127, h = rem >> 4, ci = rem & 15;
    uint4 v = ((const uint4*)Uws)[(size_t)(b0 + bt) * 128 + h * 16 + ci];
    *(uint4*)&S.u[bt][h * UR + ci * 8] = v;
  } else if (t < 272) {
    const int i = t - 256, bt = i >> 3, h = i & 7;
    S.c[bt][h] = Cws[(size_t)(b0 + bt) * 8 + h];
  }
  __syncthreads();

  // ---- S4: scores via MFMA (R5-verified): scT = X @ u^T.
  //      l-tiles >= len skipped (S5 writes zeros there regardless). ----
  {
    const int bt = w >> 2, mt = w & 3;
    const int len = bt ? len1 : len0;
    if (mt * 16 < len) {
      const int arow = mt * 16 + (lane & 15);
      const int col  = lane & 15;
      const int kb   = (lane >> 4) * 8;
      const bool hv  = (col < 8);
      f32x4 acc = {0.f, 0.f, 0.f, 0.f};
#pragma unroll
      for (int kc = 0; kc < 4; ++kc) {
        union { uint4 u4; bf16x8 b8; } a, bu;
        a.u4  = *(const uint4*)&S.Xs[bt][arow * XR + kc * 32 + kb];
        bu.u4 = *(const uint4*)&S.u[bt][(col & 7) * UR + kc * 32 + kb];
        if (!hv) bu.u4 = make_uint4(0u, 0u, 0u, 0u);
        acc = __builtin_amdgcn_mfma_f32_16x16x32_bf16(a.b8, bu.b8, acc, 0, 0, 0);
      }
      if (hv) {
        const int l0 = mt * 16 + (lane >> 4) * 4;
        const float cadd = S.c[bt][col];
        f32x4 o;
        o[0] = (acc[0] + cadd) * 0.25f;
        o[1] = (acc[1] + cadd) * 0.25f;
        o[2] = (acc[2] + cadd) * 0.25f;
        o[3] = (acc[3] + cadd) * 0.25f;
        *(f32x4*)&S.sc[bt][col][l0] = o;
      }
    }
  }
  __syncthreads();

  // ---- S5: masked softmax in place; writes ZEROS at l>=len (covers the
  //      sc garbage in skipped S4 tiles) ----
  {
    const int bt = t >> 8, h = (t >> 5) & 7, sub = t & 31;
    const int len = bt ? len1 : len0;
    const int l0 = sub, l1 = sub + 32;
    float s0 = S.sc[bt][h][l0], s1 = S.sc[bt][h][l1];
    const bool v0 = l0 < len, v1 = l1 < len;
    float m = fmaxf(v0 ? s0 : -INFINITY, v1 ? s1 : -INFINITY);
#pragma unroll
    for (int off = 16; off > 0; off >>= 1) m = fmaxf(m, __shfl_xor(m, off, 32));
    float e0 = v0 ? __expf(s0 - m) : 0.f;
    float e1 = v1 ? __expf(s1 - m) : 0.f;
    float s = e0 + e1;
#pragma unroll
    for (int off = 16; off > 0; off >>= 1) s += __shfl_xor(s, off, 32);
    float inv = 1.f / s;
    S.sc[bt][h][l0] = e0 * inv;
    S.sc[bt][h][l1] = e1 * inv;
  }
  __syncthreads();

  // ---- S6: y = P @ X via MFMA (R5-verified); y written from accumulator
  //      registers straight to ws (no LDS y, no flush phase) ----
  {
    const int bt = w >> 2, j0 = (w & 3) * 32;
    const int hA = (lane & 15) < 8 ? (lane & 15) : 7;
    const int l8 = (lane >> 4) * 8;
    const int jc0 = j0 + (lane & 15), jc1 = jc0 + 16;
    const int len = bt ? len1 : len0;
    f32x4 acc0 = {0.f,0.f,0.f,0.f}, acc1 = {0.f,0.f,0.f,0.f};
    const u16* xb = S.Xs[bt];
    {
      const int lb = l8;
      float4 pa = *(const float4*)&S.sc[bt][hA][lb];
      float4 pb = *(const float4*)&S.sc[bt][hA][lb + 4];
      union { u32 u[4]; bf16x8 b; } A, B0, B1;
      A.u[0] = pack2(pa.x, pa.y); A.u[1] = pack2(pa.z, pa.w);
      A.u[2] = pack2(pb.x, pb.y); A.u[3] = pack2(pb.z, pb.w);
#pragma unroll
      for (int jj = 0; jj < 4; ++jj) {
        u32 lo0 = xb[(lb+2*jj)*XR + jc0], hi0 = xb[(lb+2*jj+1)*XR + jc0];
        u32 lo1 = xb[(lb+2*jj)*XR + jc1], hi1 = xb[(lb+2*jj+1)*XR + jc1];
        B0.u[jj] = lo0 | (hi0 << 16);
        B1.u[jj] = lo1 | (hi1 << 16);
      }
      acc0 = __builtin_amdgcn_mfma_f32_16x16x32_bf16(A.b, B0.b, acc0, 0, 0, 0);
      acc1 = __builtin_amdgcn_mfma_f32_16x16x32_bf16(A.b, B1.b, acc1, 0, 0, 0);
    }
    if (len > 32) {
      const int lb = 32 + l8;
      float4 pa = *(const float4*)&S.sc[bt][hA][lb];
      float4 pb = *(const float4*)&S.sc[bt][hA][lb + 4];
      union { u32 u[4]; bf16x8 b; } A, B0, B1;
      A.u[0] = pack2(pa.x, pa.y); A.u[1] = pack2(pa.z, pa.w);
      A.u[2] = pack2(pb.x, pb.y); A.u[3] = pack2(pb.z, pb.w);
#pragma unroll
      for (int jj = 0; jj < 4; ++jj) {
        u32 lo0 = xb[(lb+2*jj)*XR + jc0], hi0 = xb[(lb+2*jj+1)*XR + jc0];
        u32 lo1 = xb[(lb+2*jj)*XR + jc1], hi1 = xb[(lb+2*jj+1)*XR + jc1];
        B0.u[jj] = lo0 | (hi0 << 16);
        B1.u[jj] = lo1 | (hi1 << 16);
      }
      acc0 = __builtin_amdgcn_mfma_f32_16x16x32_bf16(A.b, B0.b, acc0, 0, 0, 0);
      acc1 = __builtin_amdgcn_mfma_f32_16x16x32_bf16(A.b, B1.b, acc1, 0, 0, 0);
    }
    const int rbase = (lane >> 4) * 4;
    if (rbase < 8) {
      u16* yo = Yws + (size_t)(b0 + bt) * 1024;
#pragma unroll
      for (int r = 0; r < 4; ++r) {
        yo[(rbase + r) * 128 + j0 + (lane & 15)]      = f2b(acc0[r]);
        yo[(rbase + r) * 128 + j0 + 16 + (lane & 15)] = f2b(acc1[r]);
      }
    }
  }
}

__global__ __launch_bounds__(512, 4) void k2_kernel(
    const void* inter, const int* __restrict__ lengths,
    const u16* Uws, const float* Cws, u16* Yws, void* out)
{
  __shared__ SmemK2 S;
  const int t = threadIdx.x;
  const int b0 = blockIdx.x * 2;
  if (t < 64) {
    float v = b2f(((const u16*)inter)[t]);
    bool bad = !(fabsf(v) < 1000.f);
    u64 m = __ballot(bad);
    if (t == 0) S.isbf = (m == 0ull) ? 1 : 0;
  }
  __syncthreads();
  if (S.isbf) k2_body<true >(S, b0, t, inter, lengths, Uws, Cws, Yws, out);
  else        k2_body<false>(S, b0, t, inter, lengths, Uws, Cws, Yws, out);
}

// ===================== K3: ctx + out batched GEMMs =====================
struct __align__(16) SmemK3 {
  u16 ys[16 * YSR];    // 33024 B
  u16 ctx[16 * 136];   // 4352 B
  int isbf;
};

template<bool BF>
__device__ __forceinline__ void k3_body(SmemK3& S, int b0, int t,
    const u16* Yws, const void* w_in, const void* b_in,
    const void* w_out, const void* b_out, void* out)
{
  const int lane = t & 63, w = t >> 6;

  // stage y tile (16 batches x 1024 bf16, fully coalesced)
#pragma unroll
  for (int r = 0; r < 4; ++r) {
    int idx = t + 512 * r;                 // 0..2047
    int row = idx >> 7, ci = idx & 127;
    uint4 v = ((const uint4*)Yws)[(size_t)(b0 + row) * 128 + ci];
    *(uint4*)&S.ys[row * YSR + ci * 8] = v;
  }
  __syncthreads();

  // ctx tile: head ct = w. D[b,j] = sum_k y[b][ct*128+k] * Wv[ct16+j][k]
  {
    const int col = lane & 15, kb = (lane >> 4) * 8, rbase = (lane >> 4) * 4;
    f32x4 acc = {0.f, 0.f, 0.f, 0.f};
#pragma unroll
    for (int kc = 0; kc < 4; ++kc) {
      union { uint4 u4; bf16x8 b8; } A, Bf;
      A.u4  = *(const uint4*)&S.ys[col * YSR + w * 128 + kc * 32 + kb];
      Bf.u4 = wfrag<BF>(w_in, (size_t)(256 + w * 16 + col) * 128 + kc * 32 + kb);
      acc = __builtin_amdgcn_mfma_f32_16x16x32_bf16(A.b8, Bf.b8, acc, 0, 0, 0);
    }
    const float bv = lds1<BF>(b_in, 256 + w * 16 + col);
#pragma unroll
    for (int r = 0; r < 4; ++r)
      S.ctx[(rbase + r) * 136 + w * 16 + col] = f2b(acc[r] + bv);
  }
  __syncthreads();

  // out tile: e-tile w. D[b,e] = sum_k ctx[b,k] * Wout[e][k]
  {
    const int col = lane & 15, kb = (lane >> 4) * 8, rbase = (lane >> 4) * 4;
    f32x4 acc = {0.f, 0.f, 0.f, 0.f};
#pragma unroll
    for (int kc = 0; kc < 4; ++kc) {
      union { uint4 u4; bf16x8 b8; } A, Bf;
      A.u4  = *(const uint4*)&S.ctx[col * 136 + kc * 32 + kb];
      Bf.u4 = wfrag<BF>(w_out, (size_t)(w * 16 + col) * 128 + kc * 32 + kb);
      acc = __builtin_amdgcn_mfma_f32_16x16x32_bf16(A.b8, Bf.b8, acc, 0, 0, 0);
    }
    const float bo = lds1<BF>(b_out, w * 16 + col);
#pragma unroll
    for (int r = 0; r < 4; ++r) {
      float v = acc[r] + bo;
      size_t oo = (size_t)(b0 + rbase + r) * 128 + w * 16 + col;
      if (BF) ((u16*)out)[oo] = f2b(v);
      else    ((float*)out)[oo] = v;
    }
  }
}

__global__ __launch_bounds__(512, 4) void k3_kernel(
    const u16* Yws, const void* w_in, const void* b_in,
    const void* w_out, const void* b_out, void* out)
{
  __shared__ SmemK3 S;
  const int t = threadIdx.x;
  const int b0 = blockIdx.x * 16;
  if (t < 64) {   // probe weight dtype on w_out (nonzero uniform values)
    float v = b2f(((const u16*)w_out)[t]);
    bool bad = !(fabsf(v) < 1000.f);
    u64 m = __ballot(bad);
    if (t == 0) S.isbf = (m == 0ull) ? 1 : 0;
  }
  __syncthreads();
  if (S.isbf) k3_body<true >(S, b0, t, Yws, w_in, b_in, w_out, b_out, out);
  else        k3_body<false>(S, b0, t, Yws, w_in, b_in, w_out, b_out, out);
}

// ===================== mono fallback (R5, proven 164.8us) =====================
struct __align__(16) SmemM {
  u16   Xs[2][64 * XR];
  u16   u[2][8 * UR];
  u16   y[2][8 * YR];
  float q[2][128];
  float sc[2][8][SCR];
  float c[2][8];
  float ctx[2][128];
  int   isbf;
};

template<bool BF>
__device__ __forceinline__ void mono_body(SmemM& S, int b0, int t,
    const void* inter, const int* lengths, const void* w_in, const void* b_in,
    const void* w_out, const void* b_out, void* out)
{
  const int len0 = lengths[b0];
  const int len1 = lengths[b0 + 1];
  const int lane = t & 63, w = t >> 6;

#pragma unroll
  for (int r = 0; r < 4; ++r) {
    int g = t + 512 * r;
    int tile = g >> 10, gg = g & 1023, l = gg >> 4, ci = gg & 15;
    uint4 v = make_uint4(0u, 0u, 0u, 0u);
    if (l < (tile ? len1 : len0)) {
      if (BF) {
        v = ((const uint4*)inter)[(size_t)b0 * 1024 + g];
      } else {
        const float4* src = (const float4*)inter + (size_t)b0 * 2048;
        float4 a = src[g * 2], b = src[g * 2 + 1];
        v.x = pack2(a.x, a.y); v.y = pack2(a.z, a.w);
        v.z = pack2(b.x, b.y); v.w = pack2(b.z, b.w);
      }
    }
    ((uint4*)S.Xs[tile])[l * XR4 + ci] = v;
  }
  __syncthreads();

  {
    const int e = w * 16 + (lane & 15);
    const int btc = (lane & 15) < 2 ? (lane & 15) : 1;
    const int kb = (lane >> 4) * 8;
    f32x4 acc = {0.f, 0.f, 0.f, 0.f};
#pragma unroll
    for (int kc = 0; kc < 4; ++kc) {
      union { uint4 u4; bf16x8 b8; } A, Bf;
      A.u4  = *(const uint4*)&S.Xs[btc][kc * 32 + kb];
      Bf.u4 = wfrag<BF>(w_in, (size_t)e * 128 + kc * 32 + kb);
      acc = __builtin_amdgcn_mfma_f32_16x16x32_bf16(A.b8, Bf.b8, acc, 0, 0, 0);
    }
    if (lane < 16) {
      float bq = lds1<BF>(b_in, e);
      S.q[0][e] = acc[0] + bq;
      S.q[1][e] = acc[1] + bq;
    }
  }
  __syncthreads();

  {
    const int bt = t >> 8, h = (t >> 5) & 7, cc = t & 31;
    float a0=0.f,a1=0.f,a2=0.f,a3=0.f;
#pragma unroll
    for (int d = 0; d < 16; ++d) {
      float w4[4]; load4<BF>(w_in, (size_t)(128 + h * 16 + d) * 128 + cc * 4, w4);
      float q0 = S.q[bt][h * 16 + d];
      a0 = fmaf(w4[0], q0, a0); a1 = fmaf(w4[1], q0, a1);
      a2 = fmaf(w4[2], q0, a2); a3 = fmaf(w4[3], q0, a3);
    }
    *(uint2*)&S.u[bt][h * UR + cc * 4] = make_uint2(pack2(a0, a1), pack2(a2, a3));
    if (cc == 0) {
      float c0 = 0.f;
      for (int d = 0; d < 16; ++d)
        c0 += S.q[bt][h * 16 + d] * lds1<BF>(b_in, 128 + h * 16 + d);
      S.c[bt][h] = c0;
    }
  }
  __syncthreads();

  {
    const int bt = w >> 2, mt = w & 3;
    const int arow = mt * 16 + (lane & 15);
    const int col  = lane & 15;
    const int kb   = (lane >> 4) * 8;
    const bool hv  = (col < 8);
    f32x4 acc = {0.f, 0.f, 0.f, 0.f};
#pragma unroll
    for (int kc = 0; kc < 4; ++kc) {
      union { uint4 u4; bf16x8 b8; } a, bu;
      a.u4  = *(const uint4*)&S.Xs[bt][arow * XR + kc * 32 + kb];
      bu.u4 = *(const uint4*)&S.u[bt][(col & 7) * UR + kc * 32 + kb];
      if (!hv) bu.u4 = make_uint4(0u, 0u, 0u, 0u);
      acc = __builtin_amdgcn_mfma_f32_16x16x32_bf16(a.b8, bu.b8, acc, 0, 0, 0);
    }
    if (hv) {
      const int l0 = mt * 16 + (lane >> 4) * 4;
      const float cadd = S.c[bt][col];
      f32x4 o;
      o[0] = (acc[0] + cadd) * 0.25f;
      o[1] = (acc[1] + cadd) * 0.25f;
      o[2] = (acc[2] + cadd) * 0.25f;
      o[3] = (acc[3] + cadd) * 0.25f;
      *(f32x4*)&S.sc[bt][col][l0] = o;
    }
  }
  __syncthreads();

  {
    const int bt = t >> 8, h = (t >> 5) & 7, sub = t & 31;
    const int len = bt ? len1 : len0;
    const int l0 = sub, l1 = sub + 32;
    float s0 = S.sc[bt][h][l0], s1 = S.sc[bt][h][l1];
    const bool v0 = l0 < len, v1 = l1 < len;
    float m = fmaxf(v0 ? s0 : -INFINITY, v1 ? s1 : -INFINITY);
#pragma unroll
    for (int off = 16; off > 0; off >>= 1) m = fmaxf(m, __shfl_xor(m, off, 32));
    float e0 = v0 ? __expf(s0 - m) : 0.f;
    float e1 = v1 ? __expf(s1 - m) : 0.f;
    float s = e0 + e1;
#pragma unroll
    for (int off = 16; off > 0; off >>= 1) s += __shfl_xor(s, off, 32);
    float inv = 1.f / s;
    S.sc[bt][h][l0] = e0 * inv;
    S.sc[bt][h][l1] = e1 * inv;
  }
  __syncthreads();

  {
    const int bt = w >> 2, j0 = (w & 3) * 32;
    const int hA = (lane & 15) < 8 ? (lane & 15) : 7;
    const int l8 = (lane >> 4) * 8;
    const int jc0 = j0 + (lane & 15), jc1 = jc0 + 16;
    const int len = bt ? len1 : len0;
    f32x4 acc0 = {0.f,0.f,0.f,0.f}, acc1 = {0.f,0.f,0.f,0.f};
    const u16* xb = S.Xs[bt];
    {
      const int lb = l8;
      float4 pa = *(const float4*)&S.sc[bt][hA][lb];
      float4 pb = *(const float4*)&S.sc[bt][hA][lb + 4];
      union { u32 u[4]; bf16x8 b; } A, B0, B1;
      A.u[0] = pack2(pa.x, pa.y); A.u[1] = pack2(pa.z, pa.w);
      A.u[2] = pack2(pb.x, pb.y); A.u[3] = pack2(pb.z, pb.w);
#pragma unroll
      for (int jj = 0; jj < 4; ++jj) {
        u32 lo0 = xb[(lb+2*jj)*XR + jc0], hi0 = xb[(lb+2*jj+1)*XR + jc0];
        u32 lo1 = xb[(lb+2*jj)*XR + jc1], hi1 = xb[(lb+2*jj+1)*XR + jc1];
        B0.u[jj] = lo0 | (hi0 << 16);
        B1.u[jj] = lo1 | (hi1 << 16);
      }
      acc0 = __builtin_amdgcn_mfma_f32_16x16x32_bf16(A.b, B0.b, acc0, 0, 0, 0);
      acc1 = __builtin_amdgcn_mfma_f32_16x16x32_bf16(A.b, B1.b, acc1, 0, 0, 0);
    }
    if (len > 32) {
      const int lb = 32 + l8;
      float4 pa = *(const float4*)&S.sc[bt][hA][lb];
      float4 pb = *(const float4*)&S.sc[bt][hA][lb + 4];
      union { u32 u[4]; bf16x8 b; } A, B0, B1;
      A.u[0] = pack2(pa.x, pa.y); A.u[1] = pack2(pa.z, pa.w);
      A.u[2] = pack2(pb.x, pb.y); A.u[3] = pack2(pb.z, pb.w);
#pragma unroll
      for (int jj = 0; jj < 4; ++jj) {
        u32 lo0 = xb[(lb+2*jj)*XR + jc0], hi0 = xb[(lb+2*jj+1)*XR + jc0];
        u32 lo1 = xb[(lb+2*jj)*XR + jc1], hi1 = xb[(lb+2*jj+1)*XR + jc1];
        B0.u[jj] = lo0 | (hi0 << 16);
        B1.u[jj] = lo1 | (hi1 << 16);
      }
      acc0 = __builtin_amdgcn_mfma_f32_16x16x32_bf16(A.b, B0.b, acc0, 0, 0, 0);
      acc1 = __builtin_amdgcn_mfma_f32_16x16x32_bf16(A.b, B1.b, acc1, 0, 0, 0);
    }
    const int rbase = (lane >> 4) * 4;
    if (rbase < 8) {
#pragma unroll
      for (int r = 0; r < 4; ++r) {
        S.y[bt][(rbase + r) * YR + j0 + (lane & 15)]      = f2b(acc0[r]);
        S.y[bt][(rbase + r) * YR + j0 + 16 + (lane & 15)] = f2b(acc1[r]);
      }
    }
  }
  __syncthreads();

  {
    const int e = w * 16 + (lane & 15);
    const int btc = (lane & 15) < 2 ? (lane & 15) : 1;
    const int kb = (lane >> 4) * 8;
    f32x4 acc = {0.f, 0.f, 0.f, 0.f};
#pragma unroll
    for (int kc = 0; kc < 4; ++kc) {
      union { uint4 u4; bf16x8 b8; } A, Bf;
      A.u4  = *(const uint4*)&S.y[btc][w * YR + kc * 32 + kb];
      Bf.u4 = wfrag<BF>(w_in, (size_t)(256 + e) * 128 + kc * 32 + kb);
      acc = __builtin_amdgcn_mfma_f32_16x16x32_bf16(A.b8, Bf.b8, acc, 0, 0, 0);
    }
    if (lane < 16) {
      S.ctx[0][e] = acc[0] + lds1<BF>(b_in, 256 + e);
      S.ctx[1][e] = acc[1] + lds1<BF>(b_in, 256 + e);
    }
  }
  __syncthreads();

  {
    const int e = w * 16 + (lane & 15);
    const int btc = (lane & 15) < 2 ? (lane & 15) : 1;
    const int kb = (lane >> 4) * 8;
    f32x4 acc = {0.f, 0.f, 0.f, 0.f};
#pragma unroll
    for (int kc = 0; kc < 4; ++kc) {
      union { u32 u[4]; bf16x8 b; } A;
      union { uint4 u4; bf16x8 b8; } Bf;
      float4 ca = *(const float4*)&S.ctx[btc][kc * 32 + kb];
      float4 cb = *(const float4*)&S.ctx[btc][kc * 32 + kb + 4];
      A.u[0] = pack2(ca.x, ca.y); A.u[1] = pack2(ca.z, ca.w);
      A.u[2] = pack2(cb.x, cb.y); A.u[3] = pack2(cb.z, cb.w);
      Bf.u4 = wfrag<BF>(w_out, (size_t)e * 128 + kc * 32 + kb);
      acc = __builtin_amdgcn_mfma_f32_16x16x32_bf16(A.b, Bf.b8, acc, 0, 0, 0);
    }
    if (lane < 16) {
      float bo = lds1<BF>(b_out, e);
      float a0 = acc[0] + bo, a1 = acc[1] + bo;
      if (BF) {
        ((u16*)out)[(size_t)b0 * 128 + e]       = f2b(a0);
        ((u16*)out)[(size_t)(b0 + 1) * 128 + e] = f2b(a1);
      } else {
        ((float*)out)[(size_t)b0 * 128 + e]       = a0;
        ((float*)out)[(size_t)(b0 + 1) * 128 + e] = a1;
      }
    } else if (lane < 48) {
      const int bt = (lane >> 4) - 1;
      size_t o1 = (size_t)8192 * 128 + (size_t)(b0 + bt) * 128 + e;
      u16 xv = S.Xs[bt][e];
      if (BF) ((u16*)out)[o1] = xv;
      else    ((float*)out)[o1] = b2f(xv);
    }
  }
}

__global__ __launch_bounds__(512, 4) void mono_kernel(
    const void* inter, const int* __restrict__ lengths,
    const void* w_in, const void* b_in, const void* w_out, const void* b_out,
    void* out)
{
  __shared__ SmemM S;
  const int t = threadIdx.x;
  const int b0 = blockIdx.x * 2;
  if (t < 64) {
    float v = b2f(((const u16*)inter)[t]);
    bool bad = !(fabsf(v) < 1000.f);
    u64 m = __ballot(bad);
    if (t == 0) S.isbf = (m == 0ull) ? 1 : 0;
  }
  __syncthreads();
  if (S.isbf) mono_body<true >(S, b0, t, inter, lengths, w_in, b_in, w_out, b_out, out);
  else        mono_body<false>(S, b0, t, inter, lengths, w_in, b_in, w_out, b_out, out);
}

extern "C" void kernel_launch(void* const* d_in, const int* in_sizes, int n_in,
                              void* d_out, int out_size, void* d_ws, size_t ws_size,
                              hipStream_t stream) {
  if (d_ws && ws_size >= (size_t)WS_NEED) {
    u16*   Uws = (u16*)((char*)d_ws + WS_U_OFF);
    float* Cws = (float*)((char*)d_ws + WS_C_OFF);
    u16*   Yws = (u16*)((char*)d_ws + WS_Y_OFF);
    k1_kernel<<<dim3(1024), dim3(512), 0, stream>>>(
        d_in[0], d_in[2], d_in[3], Uws, Cws);
    k2_kernel<<<dim3(4096), dim3(512), 0, stream>>>(
        d_in[0], (const int*)d_in[1], Uws, Cws, Yws, d_out);
    k3_kernel<<<dim3(512), dim3(512), 0, stream>>>(
        Yws, d_in[2], d_in[3], d_in[4], d_in[5], d_out);
  } else {
    mono_kernel<<<dim3(4096), dim3(512), 0, stream>>>(
        d_in[0], (const int*)d_in[1], d_in[2], d_in[3], d_in[4], d_in[5], d_out);
  }
}

// Round 9
// 368.705 us; speedup vs baseline: 1.4388x; 1.0095x over previous
//
#include <hip/hip_runtime.h>
#include <hip/hip_bf16.h>

// InfoMultiAttn: B=8192, L=64, E=128, H=8, HD=16. fp32 accumulate.
// Algebraic restructure:
//   scores[h,l] = (u_h . x_l + c_h)/4,  u_h = Wk_h^T q_h,  c_h = q_h . bk_h
//   ctx_h       = Wv_h y_h + bv_h,      y_h = sum_l attn[h,l] x_l
// R11/R12 (372.2us harness, ~102us GPU): 3-kernel split via d_ws:
//   K1 q/u/c (8-batch weight amortize) | K2 attention core (no weights) |
//   K3 ctx+out GEMMs (16-batch tiles). Mono fallback = R5 (164.8us).
// R13: K2 -> NB=1 @ 256 threads, grid 8192. Same HBM traffic (no weights in
//   K2), but 22KB LDS -> 7 blocks/CU static, 2x independent blocks, barriers
//   span 4 waves not 8. Scheduling quantum halved; K2 est ~80 -> ~50us.

typedef unsigned int  u32;
typedef unsigned short u16;
typedef unsigned long long u64;

#define XR  136   // u16 per X row (272 B stride; b128 reads conflict-free)
#define XR4 17    // uint4 per X row
#define YR  136   // u16 per y row
#define UR  136   // u16 per u row
#define SCR 68    // floats per sc row
#define QR  132   // f32 per K1 q row (132%32=4 -> bank spread)
#define YSR 1032  // u16 per K3 y-stage row (2064B stride -> bank spread)

// workspace layout (bytes)
#define WS_U_OFF 0u          // u16 U[8192][1024]
#define WS_C_OFF 16777216u   // f32 c[8192][8]
#define WS_Y_OFF 17825792u   // u16 y[8192][1024]
#define WS_NEED  34603008u

typedef __attribute__((ext_vector_type(8))) __bf16 bf16x8;
typedef __attribute__((ext_vector_type(4))) float  f32x4;

__device__ __forceinline__ float blo(u32 u) { return __uint_as_float(u << 16); }
__device__ __forceinline__ float bhi(u32 u) { return __uint_as_float(u & 0xffff0000u); }
__device__ __forceinline__ float b2f(u16 u) { return __uint_as_float(((u32)u) << 16); }
__device__ __forceinline__ u16 f2b(float f) {
  union { __hip_bfloat16 h; u16 u; } cv; cv.h = __float2bfloat16(f); return cv.u;
}
__device__ __forceinline__ u32 pack2(float a, float b) {
  return (u32)f2b(a) | ((u32)f2b(b) << 16);
}

// 8 consecutive weight elems at element offset off -> bf16x8 fragment bits
template<bool BF>
__device__ __forceinline__ uint4 wfrag(const void* p, size_t off) {
  if (BF) {
    return *(const uint4*)((const u16*)p + off);
  } else {
    const float4* q4 = (const float4*)((const float*)p + off);
    float4 a = q4[0], b = q4[1];
    uint4 v;
    v.x = pack2(a.x, a.y); v.y = pack2(a.z, a.w);
    v.z = pack2(b.x, b.y); v.w = pack2(b.z, b.w);
    return v;
  }
}
template<bool BF>
__device__ __forceinline__ void load4(const void* p, size_t off, float* o) {
  if (BF) {
    uint2 v = *(const uint2*)((const u16*)p + off);
    o[0]=blo(v.x); o[1]=bhi(v.x); o[2]=blo(v.y); o[3]=bhi(v.y);
  } else {
    float4 v = *(const float4*)((const float*)p + off);
    o[0]=v.x; o[1]=v.y; o[2]=v.z; o[3]=v.w;
  }
}
template<bool BF>
__device__ __forceinline__ float lds1(const void* p, size_t off) {
  return BF ? b2f(((const u16*)p)[off]) : ((const float*)p)[off];
}

// ===================== K1: q -> U, c for all batches =====================
struct __align__(16) SmemK1 {
  u16   X0s[8 * XR];     // 2176 B (row 0 of 8 batches)
  float q[8 * QR];       // 4224 B
  int   isbf;
};

template<bool BF>
__device__ __forceinline__ void k1_body(SmemK1& S, int b0, int t,
    const void* inter, const void* w_in, const void* b_in,
    u16* Uws, float* Cws)
{
  const int lane = t & 63, w = t >> 6;

  // stage X0 (row l=0 of each batch; always valid since len>=1)
  if (t < 128) {
    const int i = t >> 4, ci = t & 15;
    const size_t bidx = (size_t)(b0 + i);
    uint4 v;
    if (BF) {
      v = ((const uint4*)inter)[bidx * 1024 + ci];
    } else {
      const float4* src = (const float4*)inter + bidx * 2048 + ci * 2;
      float4 a = src[0], b = src[1];
      v.x = pack2(a.x, a.y); v.y = pack2(a.z, a.w);
      v.z = pack2(b.x, b.y); v.w = pack2(b.z, b.w);
    }
    *(uint4*)&S.X0s[i * XR + ci * 8] = v;
  }
  __syncthreads();

  // Q = X0 @ Wq^T + bq via MFMA (A row=batch (rows>=8 garbage, D unread),
  // B = Wq row e from global; wave w -> e-tile w). Also c[b][w] = q_w . bk_w.
  {
    const int r15 = lane & 15, e = w * 16 + r15;
    const int kb = (lane >> 4) * 8, rbase = (lane >> 4) * 4;
    f32x4 acc = {0.f, 0.f, 0.f, 0.f};
#pragma unroll
    for (int kc = 0; kc < 4; ++kc) {
      union { uint4 u4; bf16x8 b8; } A, Bf;
      A.u4  = *(const uint4*)&S.X0s[(r15 & 7) * XR + kc * 32 + kb];
      Bf.u4 = wfrag<BF>(w_in, (size_t)e * 128 + kc * 32 + kb);
      acc = __builtin_amdgcn_mfma_f32_16x16x32_bf16(A.b8, Bf.b8, acc, 0, 0, 0);
    }
    const float bq  = lds1<BF>(b_in, e);
    const float bkv = lds1<BF>(b_in, 128 + e);   // bk[head w][dim r15]
    float cs[4];
#pragma unroll
    for (int r = 0; r < 4; ++r) {
      float qv = acc[r] + bq;
      if (rbase < 8) S.q[(rbase + r) * QR + e] = qv;   // D row=batch (0..7 valid)
      cs[r] = qv * bkv;
    }
#pragma unroll
    for (int off = 1; off < 16; off <<= 1) {
      cs[0] += __shfl_xor(cs[0], off, 64);
      cs[1] += __shfl_xor(cs[1], off, 64);
      cs[2] += __shfl_xor(cs[2], off, 64);
      cs[3] += __shfl_xor(cs[3], off, 64);
    }
    if (r15 == 0 && rbase < 8) {
#pragma unroll
      for (int r = 0; r < 4; ++r)
        Cws[(size_t)(b0 + rbase + r) * 8 + w] = cs[r];
    }
  }
  __syncthreads();

  // U[h][j] = sum_d q[h16+d] Wk[h16+d][j]; weights OUTER, batch INNER:
  // thread = (h: t>>6, cc: (t&63)>>1, s: t&1); s covers batches 4s..4s+3.
  {
    const int h = t >> 6, rem = t & 63;
    const int cc = rem >> 1, s = rem & 1;
    float a[4][4] = {{0.f,0.f,0.f,0.f},{0.f,0.f,0.f,0.f},
                     {0.f,0.f,0.f,0.f},{0.f,0.f,0.f,0.f}};
#pragma unroll
    for (int d = 0; d < 16; ++d) {
      float w4[4]; load4<BF>(w_in, (size_t)(128 + h * 16 + d) * 128 + cc * 4, w4);
#pragma unroll
      for (int bi = 0; bi < 4; ++bi) {
        float q0 = S.q[(s * 4 + bi) * QR + h * 16 + d];
        a[bi][0] = fmaf(w4[0], q0, a[bi][0]);
        a[bi][1] = fmaf(w4[1], q0, a[bi][1]);
        a[bi][2] = fmaf(w4[2], q0, a[bi][2]);
        a[bi][3] = fmaf(w4[3], q0, a[bi][3]);
      }
    }
#pragma unroll
    for (int bi = 0; bi < 4; ++bi) {
      const int bt = s * 4 + bi;
      *(uint2*)&Uws[(size_t)(b0 + bt) * 1024 + h * 128 + cc * 4] =
          make_uint2(pack2(a[bi][0], a[bi][1]), pack2(a[bi][2], a[bi][3]));
    }
  }
}

__global__ __launch_bounds__(512, 4) void k1_kernel(
    const void* inter, const void* w_in, const void* b_in,
    u16* Uws, float* Cws)
{
  __shared__ SmemK1 S;
  const int t = threadIdx.x;
  const int b0 = blockIdx.x * 8;
  if (t < 64) {
    float v = b2f(((const u16*)inter)[t]);
    bool bad = !(fabsf(v) < 1000.f);
    u64 m = __ballot(bad);
    if (t == 0) S.isbf = (m == 0ull) ? 1 : 0;
  }
  __syncthreads();
  if (S.isbf) k1_body<true >(S, b0, t, inter, w_in, b_in, Uws, Cws);
  else        k1_body<false>(S, b0, t, inter, w_in, b_in, Uws, Cws);
}

// ===================== K2: attention core (no weights), NB=1 @256thr =========
struct __align__(16) SmemK2 {
  u16   Xs[64 * XR];    // 17408 B (rows>=len ZEROED)
  u16   u[8 * UR];      // 2176 B
  float sc[8][SCR];     // 2176 B (zeros at l>=len after softmax)
  float c[8];           // 32 B
  int   isbf;
};                       // ~21.8 KB -> 7 blocks/CU (LDS), 8 (waves)

template<bool BF>
__device__ __forceinline__ void k2_body(SmemK2& S, int b, int t,
    const void* inter, const int* lengths, const u16* Uws, const float* Cws,
    u16* Yws, void* out)
{
  const int len = lengths[b];
  const int lane = t & 63, w = t >> 6;

  // ---- S1: stage X (zero-fill rows>=len); l==0 stagers also emit the
  //      query-passthrough from registers. Then u,c from ws. ----
#pragma unroll
  for (int r = 0; r < 4; ++r) {
    int g = t + 256 * r;                    // 0..1023
    int l = g >> 4, ci = g & 15;
    uint4 v = make_uint4(0u, 0u, 0u, 0u);
    if (l < len) {
      if (BF) {
        v = ((const uint4*)inter)[(size_t)b * 1024 + g];
        if (l == 0)
          ((uint4*)out)[131072 + (size_t)b * 16 + ci] = v;
      } else {
        const float4* src = (const float4*)inter + (size_t)b * 2048;
        float4 a = src[g * 2], bb = src[g * 2 + 1];
        if (l == 0) {
          float4* o4 = (float4*)out + 262144 + (size_t)b * 32 + ci * 2;
          o4[0] = a; o4[1] = bb;               // exact fp32 passthrough
        }
        v.x = pack2(a.x, a.y); v.y = pack2(a.z, a.w);
        v.z = pack2(bb.x, bb.y); v.w = pack2(bb.z, bb.w);
      }
    }
    ((uint4*)S.Xs)[l * XR4 + ci] = v;
  }
  if (t < 128) {
    const int h = t >> 4, ci = t & 15;
    uint4 v = ((const uint4*)Uws)[(size_t)b * 128 + h * 16 + ci];
    *(uint4*)&S.u[h * UR + ci * 8] = v;
  } else if (t < 136) {
    const int h = t - 128;
    S.c[h] = Cws[(size_t)b * 8 + h];
  }
  __syncthreads();

  // ---- S4: scores via MFMA (R5-verified): scT = X @ u^T.
  //      wave w = l-tile; tiles >= len skipped (S5 zeros those slots). ----
  if (w * 16 < len) {
    const int arow = w * 16 + (lane & 15);
    const int col  = lane & 15;
    const int kb   = (lane >> 4) * 8;
    const bool hv  = (col < 8);
    f32x4 acc = {0.f, 0.f, 0.f, 0.f};
#pragma unroll
    for (int kc = 0; kc < 4; ++kc) {
      union { uint4 u4; bf16x8 b8; } a, bu;
      a.u4  = *(const uint4*)&S.Xs[arow * XR + kc * 32 + kb];
      bu.u4 = *(const uint4*)&S.u[(col & 7) * UR + kc * 32 + kb];
      if (!hv) bu.u4 = make_uint4(0u, 0u, 0u, 0u);
      acc = __builtin_amdgcn_mfma_f32_16x16x32_bf16(a.b8, bu.b8, acc, 0, 0, 0);
    }
    if (hv) {
      const int l0 = w * 16 + (lane >> 4) * 4;
      const float cadd = S.c[col];
      f32x4 o;
      o[0] = (acc[0] + cadd) * 0.25f;
      o[1] = (acc[1] + cadd) * 0.25f;
      o[2] = (acc[2] + cadd) * 0.25f;
      o[3] = (acc[3] + cadd) * 0.25f;
      *(f32x4*)&S.sc[col][l0] = o;
    }
  }
  __syncthreads();

  // ---- S5: masked softmax in place; writes ZEROS at l>=len ----
  {
    const int h = t >> 5, sub = t & 31;
    const int l0 = sub, l1 = sub + 32;
    float s0 = S.sc[h][l0], s1 = S.sc[h][l1];
    const bool v0 = l0 < len, v1 = l1 < len;
    float m = fmaxf(v0 ? s0 : -INFINITY, v1 ? s1 : -INFINITY);
#pragma unroll
    for (int off = 16; off > 0; off >>= 1) m = fmaxf(m, __shfl_xor(m, off, 32));
    float e0 = v0 ? __expf(s0 - m) : 0.f;
    float e1 = v1 ? __expf(s1 - m) : 0.f;
    float s = e0 + e1;
#pragma unroll
    for (int off = 16; off > 0; off >>= 1) s += __shfl_xor(s, off, 32);
    float inv = 1.f / s;
    S.sc[h][l0] = e0 * inv;
    S.sc[h][l1] = e1 * inv;
  }
  __syncthreads();

  // ---- S6: y = P @ X via MFMA (R5-verified); wave w = j-pair w*32.
  //      y written from accumulators straight to ws. ----
  {
    const int j0 = w * 32;
    const int hA = (lane & 15) < 8 ? (lane & 15) : 7;
    const int l8 = (lane >> 4) * 8;
    const int jc0 = j0 + (lane & 15), jc1 = jc0 + 16;
    f32x4 acc0 = {0.f,0.f,0.f,0.f}, acc1 = {0.f,0.f,0.f,0.f};
    const u16* xb = S.Xs;
    {
      const int lb = l8;
      float4 pa = *(const float4*)&S.sc[hA][lb];
      float4 pb = *(const float4*)&S.sc[hA][lb + 4];
      union { u32 u[4]; bf16x8 b; } A, B0, B1;
      A.u[0] = pack2(pa.x, pa.y); A.u[1] = pack2(pa.z, pa.w);
      A.u[2] = pack2(pb.x, pb.y); A.u[3] = pack2(pb.z, pb.w);
#pragma unroll
      for (int jj = 0; jj < 4; ++jj) {
        u32 lo0 = xb[(lb+2*jj)*XR + jc0], hi0 = xb[(lb+2*jj+1)*XR + jc0];
        u32 lo1 = xb[(lb+2*jj)*XR + jc1], hi1 = xb[(lb+2*jj+1)*XR + jc1];
        B0.u[jj] = lo0 | (hi0 << 16);
        B1.u[jj] = lo1 | (hi1 << 16);
      }
      acc0 = __builtin_amdgcn_mfma_f32_16x16x32_bf16(A.b, B0.b, acc0, 0, 0, 0);
      acc1 = __builtin_amdgcn_mfma_f32_16x16x32_bf16(A.b, B1.b, acc1, 0, 0, 0);
    }
    if (len > 32) {
      const int lb = 32 + l8;
      float4 pa = *(const float4*)&S.sc[hA][lb];
      float4 pb = *(const float4*)&S.sc[hA][lb + 4];
      union { u32 u[4]; bf16x8 b; } A, B0, B1;
      A.u[0] = pack2(pa.x, pa.y); A.u[1] = pack2(pa.z, pa.w);
      A.u[2] = pack2(pb.x, pb.y); A.u[3] = pack2(pb.z, pb.w);
#pragma unroll
      for (int jj = 0; jj < 4; ++jj) {
        u32 lo0 = xb[(lb+2*jj)*XR + jc0], hi0 = xb[(lb+2*jj+1)*XR + jc0];
        u32 lo1 = xb[(lb+2*jj)*XR + jc1], hi1 = xb[(lb+2*jj+1)*XR + jc1];
        B0.u[jj] = lo0 | (hi0 << 16);
        B1.u[jj] = lo1 | (hi1 << 16);
      }
      acc0 = __builtin_amdgcn_mfma_f32_16x16x32_bf16(A.b, B0.b, acc0, 0, 0, 0);
      acc1 = __builtin_amdgcn_mfma_f32_16x16x32_bf16(A.b, B1.b, acc1, 0, 0, 0);
    }
    const int rbase = (lane >> 4) * 4;
    if (rbase < 8) {
      u16* yo = Yws + (size_t)b * 1024;
#pragma unroll
      for (int r = 0; r < 4; ++r) {
        yo[(rbase + r) * 128 + j0 + (lane & 15)]      = f2b(acc0[r]);
        yo[(rbase + r) * 128 + j0 + 16 + (lane & 15)] = f2b(acc1[r]);
      }
    }
  }
}

__global__ __launch_bounds__(256, 4) void k2_kernel(
    const void* inter, const int* __restrict__ lengths,
    const u16* Uws, const float* Cws, u16* Yws, void* out)
{
  __shared__ SmemK2 S;
  const int t = threadIdx.x;
  const int b = blockIdx.x;
  if (t < 64) {
    float v = b2f(((const u16*)inter)[t]);
    bool bad = !(fabsf(v) < 1000.f);
    u64 m = __ballot(bad);
    if (t == 0) S.isbf = (m == 0ull) ? 1 : 0;
  }
  __syncthreads();
  if (S.isbf) k2_body<true >(S, b, t, inter, lengths, Uws, Cws, Yws, out);
  else        k2_body<false>(S, b, t, inter, lengths, Uws, Cws, Yws, out);
}

// ===================== K3: ctx + out batched GEMMs =====================
struct __align__(16) SmemK3 {
  u16 ys[16 * YSR];    // 33024 B
  u16 ctx[16 * 136];   // 4352 B
  int isbf;
};

template<bool BF>
__device__ __forceinline__ void k3_body(SmemK3& S, int b0, int t,
    const u16* Yws, const void* w_in, const void* b_in,
    const void* w_out, const void* b_out, void* out)
{
  const int lane = t & 63, w = t >> 6;

  // stage y tile (16 batches x 1024 bf16, fully coalesced)
#pragma unroll
  for (int r = 0; r < 4; ++r) {
    int idx = t + 512 * r;                 // 0..2047
    int row = idx >> 7, ci = idx & 127;
    uint4 v = ((const uint4*)Yws)[(size_t)(b0 + row) * 128 + ci];
    *(uint4*)&S.ys[row * YSR + ci * 8] = v;
  }
  __syncthreads();

  // ctx tile: head ct = w. D[b,j] = sum_k y[b][ct*128+k] * Wv[ct16+j][k]
  {
    const int col = lane & 15, kb = (lane >> 4) * 8, rbase = (lane >> 4) * 4;
    f32x4 acc = {0.f, 0.f, 0.f, 0.f};
#pragma unroll
    for (int kc = 0; kc < 4; ++kc) {
      union { uint4 u4; bf16x8 b8; } A, Bf;
      A.u4  = *(const uint4*)&S.ys[col * YSR + w * 128 + kc * 32 + kb];
      Bf.u4 = wfrag<BF>(w_in, (size_t)(256 + w * 16 + col) * 128 + kc * 32 + kb);
      acc = __builtin_amdgcn_mfma_f32_16x16x32_bf16(A.b8, Bf.b8, acc, 0, 0, 0);
    }
    const float bv = lds1<BF>(b_in, 256 + w * 16 + col);
#pragma unroll
    for (int r = 0; r < 4; ++r)
      S.ctx[(rbase + r) * 136 + w * 16 + col] = f2b(acc[r] + bv);
  }
  __syncthreads();

  // out tile: e-tile w. D[b,e] = sum_k ctx[b,k] * Wout[e][k]
  {
    const int col = lane & 15, kb = (lane >> 4) * 8, rbase = (lane >> 4) * 4;
    f32x4 acc = {0.f, 0.f, 0.f, 0.f};
#pragma unroll
    for (int kc = 0; kc < 4; ++kc) {
      union { uint4 u4; bf16x8 b8; } A, Bf;
      A.u4  = *(const uint4*)&S.ctx[col * 136 + kc * 32 + kb];
      Bf.u4 = wfrag<BF>(w_out, (size_t)(w * 16 + col) * 128 + kc * 32 + kb);
      acc = __builtin_amdgcn_mfma_f32_16x16x32_bf16(A.b8, Bf.b8, acc, 0, 0, 0);
    }
    const float bo = lds1<BF>(b_out, w * 16 + col);
#pragma unroll
    for (int r = 0; r < 4; ++r) {
      float v = acc[r] + bo;
      size_t oo = (size_t)(b0 + rbase + r) * 128 + w * 16 + col;
      if (BF) ((u16*)out)[oo] = f2b(v);
      else    ((float*)out)[oo] = v;
    }
  }
}

__global__ __launch_bounds__(512, 4) void k3_kernel(
    const u16* Yws, const void* w_in, const void* b_in,
    const void* w_out, const void* b_out, void* out)
{
  __shared__ SmemK3 S;
  const int t = threadIdx.x;
  const int b0 = blockIdx.x * 16;
  if (t < 64) {   // probe weight dtype on w_out (nonzero uniform values)
    float v = b2f(((const u16*)w_out)[t]);
    bool bad = !(fabsf(v) < 1000.f);
    u64 m = __ballot(bad);
    if (t == 0) S.isbf = (m == 0ull) ? 1 : 0;
  }
  __syncthreads();
  if (S.isbf) k3_body<true >(S, b0, t, Yws, w_in, b_in, w_out, b_out, out);
  else        k3_body<false>(S, b0, t, Yws, w_in, b_in, w_out, b_out, out);
}

// ===================== mono fallback (R5, proven 164.8us) =====================
struct __align__(16) SmemM {
  u16   Xs[2][64 * XR];
  u16   u[2][8 * UR];
  u16   y[2][8 * YR];
  float q[2][128];
  float sc[2][8][SCR];
  float c[2][8];
  float ctx[2][128];
  int   isbf;
};

template<bool BF>
__device__ __forceinline__ void mono_body(SmemM& S, int b0, int t,
    const void* inter, const int* lengths, const void* w_in, const void* b_in,
    const void* w_out, const void* b_out, void* out)
{
  const int len0 = lengths[b0];
  const int len1 = lengths[b0 + 1];
  const int lane = t & 63, w = t >> 6;

#pragma unroll
  for (int r = 0; r < 4; ++r) {
    int g = t + 512 * r;
    int tile = g >> 10, gg = g & 1023, l = gg >> 4, ci = gg & 15;
    uint4 v = make_uint4(0u, 0u, 0u, 0u);
    if (l < (tile ? len1 : len0)) {
      if (BF) {
        v = ((const uint4*)inter)[(size_t)b0 * 1024 + g];
      } else {
        const float4* src = (const float4*)inter + (size_t)b0 * 2048;
        float4 a = src[g * 2], b = src[g * 2 + 1];
        v.x = pack2(a.x, a.y); v.y = pack2(a.z, a.w);
        v.z = pack2(b.x, b.y); v.w = pack2(b.z, b.w);
      }
    }
    ((uint4*)S.Xs[tile])[l * XR4 + ci] = v;
  }
  __syncthreads();

  {
    const int e = w * 16 + (lane & 15);
    const int btc = (lane & 15) < 2 ? (lane & 15) : 1;
    const int kb = (lane >> 4) * 8;
    f32x4 acc = {0.f, 0.f, 0.f, 0.f};
#pragma unroll
    for (int kc = 0; kc < 4; ++kc) {
      union { uint4 u4; bf16x8 b8; } A, Bf;
      A.u4  = *(const uint4*)&S.Xs[btc][kc * 32 + kb];
      Bf.u4 = wfrag<BF>(w_in, (size_t)e * 128 + kc * 32 + kb);
      acc = __builtin_amdgcn_mfma_f32_16x16x32_bf16(A.b8, Bf.b8, acc, 0, 0, 0);
    }
    if (lane < 16) {
      float bq = lds1<BF>(b_in, e);
      S.q[0][e] = acc[0] + bq;
      S.q[1][e] = acc[1] + bq;
    }
  }
  __syncthreads();

  {
    const int bt = t >> 8, h = (t >> 5) & 7, cc = t & 31;
    float a0=0.f,a1=0.f,a2=0.f,a3=0.f;
#pragma unroll
    for (int d = 0; d < 16; ++d) {
      float w4[4]; load4<BF>(w_in, (size_t)(128 + h * 16 + d) * 128 + cc * 4, w4);
      float q0 = S.q[bt][h * 16 + d];
      a0 = fmaf(w4[0], q0, a0); a1 = fmaf(w4[1], q0, a1);
      a2 = fmaf(w4[2], q0, a2); a3 = fmaf(w4[3], q0, a3);
    }
    *(uint2*)&S.u[bt][h * UR + cc * 4] = make_uint2(pack2(a0, a1), pack2(a2, a3));
    if (cc == 0) {
      float c0 = 0.f;
      for (int d = 0; d < 16; ++d)
        c0 += S.q[bt][h * 16 + d] * lds1<BF>(b_in, 128 + h * 16 + d);
      S.c[bt][h] = c0;
    }
  }
  __syncthreads();

  {
    const int bt = w >> 2, mt = w & 3;
    const int arow = mt * 16 + (lane & 15);
    const int col  = lane & 15;
    const int kb   = (lane >> 4) * 8;
    const bool hv  = (col < 8);
    f32x4 acc = {0.f, 0.f, 0.f, 0.f};
#pragma unroll
    for (int kc = 0; kc < 4; ++kc) {
      union { uint4 u4; bf16x8 b8; } a, bu;
      a.u4  = *(const uint4*)&S.Xs[bt][arow * XR + kc * 32 + kb];
      bu.u4 = *(const uint4*)&S.u[bt][(col & 7) * UR + kc * 32 + kb];
      if (!hv) bu.u4 = make_uint4(0u, 0u, 0u, 0u);
      acc = __builtin_amdgcn_mfma_f32_16x16x32_bf16(a.b8, bu.b8, acc, 0, 0, 0);
    }
    if (hv) {
      const int l0 = mt * 16 + (lane >> 4) * 4;
      const float cadd = S.c[bt][col];
      f32x4 o;
      o[0] = (acc[0] + cadd) * 0.25f;
      o[1] = (acc[1] + cadd) * 0.25f;
      o[2] = (acc[2] + cadd) * 0.25f;
      o[3] = (acc[3] + cadd) * 0.25f;
      *(f32x4*)&S.sc[bt][col][l0] = o;
    }
  }
  __syncthreads();

  {
    const int bt = t >> 8, h = (t >> 5) & 7, sub = t & 31;
    const int len = bt ? len1 : len0;
    const int l0 = sub, l1 = sub + 32;
    float s0 = S.sc[bt][h][l0], s1 = S.sc[bt][h][l1];
    const bool v0 = l0 < len, v1 = l1 < len;
    float m = fmaxf(v0 ? s0 : -INFINITY, v1 ? s1 : -INFINITY);
#pragma unroll
    for (int off = 16; off > 0; off >>= 1) m = fmaxf(m, __shfl_xor(m, off, 32));
    float e0 = v0 ? __expf(s0 - m) : 0.f;
    float e1 = v1 ? __expf(s1 - m) : 0.f;
    float s = e0 + e1;
#pragma unroll
    for (int off = 16; off > 0; off >>= 1) s += __shfl_xor(s, off, 32);
    float inv = 1.f / s;
    S.sc[bt][h][l0] = e0 * inv;
    S.sc[bt][h][l1] = e1 * inv;
  }
  __syncthreads();

  {
    const int bt = w >> 2, j0 = (w & 3) * 32;
    const int hA = (lane & 15) < 8 ? (lane & 15) : 7;
    const int l8 = (lane >> 4) * 8;
    const int jc0 = j0 + (lane & 15), jc1 = jc0 + 16;
    const int len = bt ? len1 : len0;
    f32x4 acc0 = {0.f,0.f,0.f,0.f}, acc1 = {0.f,0.f,0.f,0.f};
    const u16* xb = S.Xs[bt];
    {
      const int lb = l8;
      float4 pa = *(const float4*)&S.sc[bt][hA][lb];
      float4 pb = *(const float4*)&S.sc[bt][hA][lb + 4];
      union { u32 u[4]; bf16x8 b; } A, B0, B1;
      A.u[0] = pack2(pa.x, pa.y); A.u[1] = pack2(pa.z, pa.w);
      A.u[2] = pack2(pb.x, pb.y); A.u[3] = pack2(pb.z, pb.w);
#pragma unroll
      for (int jj = 0; jj < 4; ++jj) {
        u32 lo0 = xb[(lb+2*jj)*XR + jc0], hi0 = xb[(lb+2*jj+1)*XR + jc0];
        u32 lo1 = xb[(lb+2*jj)*XR + jc1], hi1 = xb[(lb+2*jj+1)*XR + jc1];
        B0.u[jj] = lo0 | (hi0 << 16);
        B1.u[jj] = lo1 | (hi1 << 16);
      }
      acc0 = __builtin_amdgcn_mfma_f32_16x16x32_bf16(A.b, B0.b, acc0, 0, 0, 0);
      acc1 = __builtin_amdgcn_mfma_f32_16x16x32_bf16(A.b, B1.b, acc1, 0, 0, 0);
    }
    if (len > 32) {
      const int lb = 32 + l8;
      float4 pa = *(const float4*)&S.sc[bt][hA][lb];
      float4 pb = *(const float4*)&S.sc[bt][hA][lb + 4];
      union { u32 u[4]; bf16x8 b; } A, B0, B1;
      A.u[0] = pack2(pa.x, pa.y); A.u[1] = pack2(pa.z, pa.w);
      A.u[2] = pack2(pb.x, pb.y); A.u[3] = pack2(pb.z, pb.w);
#pragma unroll
      for (int jj = 0; jj < 4; ++jj) {
        u32 lo0 = xb[(lb+2*jj)*XR + jc0], hi0 = xb[(lb+2*jj+1)*XR + jc0];
        u32 lo1 = xb[(lb+2*jj)*XR + jc1], hi1 = xb[(lb+2*jj+1)*XR + jc1];
        B0.u[jj] = lo0 | (hi0 << 16);
        B1.u[jj] = lo1 | (hi1 << 16);
      }
      acc0 = __builtin_amdgcn_mfma_f32_16x16x32_bf16(A.b, B0.b, acc0, 0, 0, 0);
      acc1 = __builtin_amdgcn_mfma_f32_16x16x32_bf16(A.b, B1.b, acc1, 0, 0, 0);
    }
    const int rbase = (lane >> 4) * 4;
    if (rbase < 8) {
#pragma unroll
      for (int r = 0; r < 4; ++r) {
        S.y[bt][(rbase + r) * YR + j0 + (lane & 15)]      = f2b(acc0[r]);
        S.y[bt][(rbase + r) * YR + j0 + 16 + (lane & 15)] = f2b(acc1[r]);
      }
    }
  }
  __syncthreads();

  {
    const int e = w * 16 + (lane & 15);
    const int btc = (lane & 15) < 2 ? (lane & 15) : 1;
    const int kb = (lane >> 4) * 8;
    f32x4 acc = {0.f, 0.f, 0.f, 0.f};
#pragma unroll
    for (int kc = 0; kc < 4; ++kc) {
      union { uint4 u4; bf16x8 b8; } A, Bf;
      A.u4  = *(const uint4*)&S.y[btc][w * YR + kc * 32 + kb];
      Bf.u4 = wfrag<BF>(w_in, (size_t)(256 + e) * 128 + kc * 32 + kb);
      acc = __builtin_amdgcn_mfma_f32_16x16x32_bf16(A.b8, Bf.b8, acc, 0, 0, 0);
    }
    if (lane < 16) {
      S.ctx[0][e] = acc[0] + lds1<BF>(b_in, 256 + e);
      S.ctx[1][e] = acc[1] + lds1<BF>(b_in, 256 + e);
    }
  }
  __syncthreads();

  {
    const int e = w * 16 + (lane & 15);
    const int btc = (lane & 15) < 2 ? (lane & 15) : 1;
    const int kb = (lane >> 4) * 8;
    f32x4 acc = {0.f, 0.f, 0.f, 0.f};
#pragma unroll
    for (int kc = 0; kc < 4; ++kc) {
      union { u32 u[4]; bf16x8 b; } A;
      union { uint4 u4; bf16x8 b8; } Bf;
      float4 ca = *(const float4*)&S.ctx[btc][kc * 32 + kb];
      float4 cb = *(const float4*)&S.ctx[btc][kc * 32 + kb + 4];
      A.u[0] = pack2(ca.x, ca.y); A.u[1] = pack2(ca.z, ca.w);
      A.u[2] = pack2(cb.x, cb.y); A.u[3] = pack2(cb.z, cb.w);
      Bf.u4 = wfrag<BF>(w_out, (size_t)e * 128 + kc * 32 + kb);
      acc = __builtin_amdgcn_mfma_f32_16x16x32_bf16(A.b, Bf.b8, acc, 0, 0, 0);
    }
    if (lane < 16) {
      float bo = lds1<BF>(b_out, e);
      float a0 = acc[0] + bo, a1 = acc[1] + bo;
      if (BF) {
        ((u16*)out)[(size_t)b0 * 128 + e]       = f2b(a0);
        ((u16*)out)[(size_t)(b0 + 1) * 128 + e] = f2b(a1);
      } else {
        ((float*)out)[(size_t)b0 * 128 + e]       = a0;
        ((float*)out)[(size_t)(b0 + 1) * 128 + e] = a1;
      }
    } else if (lane < 48) {
      const int bt = (lane >> 4) - 1;
      size_t o1 = (size_t)8192 * 128 + (size_t)(b0 + bt) * 128 + e;
      u16 xv = S.Xs[bt][e];
      if (BF) ((u16*)out)[o1] = xv;
      else    ((float*)out)[o1] = b2f(xv);
    }
  }
}

__global__ __launch_bounds__(512, 4) void mono_kernel(
    const void* inter, const int* __restrict__ lengths,
    const void* w_in, const void* b_in, const void* w_out, const void* b_out,
    void* out)
{
  __shared__ SmemM S;
  const int t = threadIdx.x;
  const int b0 = blockIdx.x * 2;
  if (t < 64) {
    float v = b2f(((const u16*)inter)[t]);
    bool bad = !(fabsf(v) < 1000.f);
    u64 m = __ballot(bad);
    if (t == 0) S.isbf = (m == 0ull) ? 1 : 0;
  }
  __syncthreads();
  if (S.isbf) mono_body<true >(S, b0, t, inter, lengths, w_in, b_in, w_out, b_out, out);
  else        mono_body<false>(S, b0, t, inter, lengths, w_in, b_in, w_out, b_out, out);
}

extern "C" void kernel_launch(void* const* d_in, const int* in_sizes, int n_in,
                              void* d_out, int out_size, void* d_ws, size_t ws_size,
                              hipStream_t stream) {
  if (d_ws && ws_size >= (size_t)WS_NEED) {
    u16*   Uws = (u16*)((char*)d_ws + WS_U_OFF);
    float* Cws = (float*)((char*)d_ws + WS_C_OFF);
    u16*   Yws = (u16*)((char*)d_ws + WS_Y_OFF);
    k1_kernel<<<dim3(1024), dim3(512), 0, stream>>>(
        d_in[0], d_in[2], d_in[3], Uws, Cws);
    k2_kernel<<<dim3(8192), dim3(256), 0, stream>>>(
        d_in[0], (const int*)d_in[1], Uws, Cws, Yws, d_out);
    k3_kernel<<<dim3(512), dim3(512), 0, stream>>>(
        Yws, d_in[2], d_in[3], d_in[4], d_in[5], d_out);
  } else {
    mono_kernel<<<dim3(4096), dim3(512), 0, stream>>>(
        d_in[0], (const int*)d_in[1], d_in[2], d_in[3], d_in[4], d_in[5], d_out);
  }
}